// Round 7
// baseline (374.087 us; speedup 1.0000x reference)
//
#include <hip/hip_runtime.h>

#define HIDDEN 2048
#define NQ     1024
#define NCTX   2048
#define NTOT   3072
#define NHEADS 32
#define KVH    8
#define HD     128

typedef __attribute__((ext_vector_type(8))) __bf16 bf16x8;
typedef __attribute__((ext_vector_type(4))) __bf16 bf16x4;
typedef __attribute__((ext_vector_type(4))) float  f32x4;

#define MFMA16(a, b, c) __builtin_amdgcn_mfma_f32_16x16x32_bf16(a, b, c, 0, 0, 0)

// Fixed softmax shift (Cauchy-Schwarz: |q|=1 after folded 1/sqrt(d), |k|=sqrt(128),
// RoPE norm-preserving => s <= 11.4 incl. bf16 rounding).
#define MSTATIC 12.0f

__device__ __forceinline__ void load_lds16(const void* g, void* l) {
    __builtin_amdgcn_global_load_lds(
        (const __attribute__((address_space(1))) unsigned int*)g,
        (__attribute__((address_space(3))) unsigned int*)l, 16, 0, 0);
}

// ---------------------------------------------------------------------------
// 4-way fused fp32 -> bf16 convert (activations + k/v weights)
// ---------------------------------------------------------------------------
__global__ __launch_bounds__(256) void conv4_f32_bf16(const float* __restrict__ s0,
                                                      __bf16* __restrict__ d0, int n0,
                                                      const float* __restrict__ s1,
                                                      __bf16* __restrict__ d1, int n1,
                                                      const float* __restrict__ s2,
                                                      __bf16* __restrict__ d2, int n2,
                                                      const float* __restrict__ s3,
                                                      __bf16* __restrict__ d3, int n3) {
    const float* s; __bf16* d; int n;
    switch (blockIdx.y) {
        case 0:  s = s0; d = d0; n = n0; break;
        case 1:  s = s1; d = d1; n = n1; break;
        case 2:  s = s2; d = d2; n = n2; break;
        default: s = s3; d = d3; n = n3; break;
    }
    int i = blockIdx.x * 256 + threadIdx.x;
    int stride = gridDim.x * 256;
    for (; i < n; i += stride) {
        float4 v = ((const float4*)s)[i];
        bf16x4 o;
        o[0] = (__bf16)v.x; o[1] = (__bf16)v.y;
        o[2] = (__bf16)v.z; o[3] = (__bf16)v.w;
        ((bf16x4*)d)[i] = o;
    }
}

// ---------------------------------------------------------------------------
// 256x64 MFMA GEMM tile bodies (R11-verified: delivery-bound fix, 9.8 B/KFLOP).
// XOR bank-swizzle (R8-verified): linear LDS dest + pre-swizzled global source
// + swizzled read.
//   bb: both operands bf16, pure async global->LDS staging (zero VALU).
//   fb: A bf16 async; B fp32 reg-staged one K-step ahead (T14), cvt->LDS.
// ---------------------------------------------------------------------------
__device__ __forceinline__ void gemm_compute256(const __bf16 (&As)[256][64],
                                                const __bf16 (&Bs)[64][64],
                                                f32x4 (&acc)[4][4],
                                                int wm, int n16, int quad, int rx) {
#pragma unroll
    for (int ks = 0; ks < 2; ks++) {
        bf16x8 af[4], bfr[4];
#pragma unroll
        for (int i = 0; i < 4; i++)
            af[i] = *(const bf16x8*)&As[wm + i * 16 + n16][((ks * 4 + quad) ^ rx) * 8];
#pragma unroll
        for (int j = 0; j < 4; j++)
            bfr[j] = *(const bf16x8*)&Bs[j * 16 + n16][((ks * 4 + quad) ^ rx) * 8];
#pragma unroll
        for (int i = 0; i < 4; i++)
#pragma unroll
            for (int j = 0; j < 4; j++)
                acc[i][j] = MFMA16(af[i], bfr[j], acc[i][j]);
    }
}

template <typename OutT>
__device__ __forceinline__ void gemm_epi256(const f32x4 (&acc)[4][4],
                                            OutT* __restrict__ Cblk, int ldc,
                                            int wm, int n16, int quad) {
#pragma unroll
    for (int i = 0; i < 4; i++)
#pragma unroll
        for (int j = 0; j < 4; j++)
#pragma unroll
            for (int r = 0; r < 4; r++)
                Cblk[(long)(wm + i * 16 + quad * 4 + r) * ldc + j * 16 + n16] =
                    (OutT)acc[i][j][r];
}

template <typename OutT>
__device__ __forceinline__ void gemm25664_bb(__bf16 (&As)[256][64], __bf16 (&Bs)[64][64],
                                             const __bf16* __restrict__ Ablk,
                                             const __bf16* __restrict__ Bblk,
                                             OutT* __restrict__ Cblk,
                                             int K, int lda, int ldb, int ldc) {
    const int tid  = threadIdx.x;
    const int lane = tid & 63;
    const int w    = tid >> 6;
    const int n16  = lane & 15;
    const int quad = lane >> 4;
    const int wm   = w * 64;                      // wave's 64-row m-slab

    f32x4 acc[4][4];
    const f32x4 fzero = {0.f, 0.f, 0.f, 0.f};
#pragma unroll
    for (int i = 0; i < 4; i++)
#pragma unroll
        for (int j = 0; j < 4; j++) acc[i][j] = fzero;

    // Linear LDS dest (gload_lds: wave-uniform base + lane*16); source col
    // pre-XORed so LDS[r][chunk c] holds global chunk c^(r&7).
    const int arow  = w * 64 + (lane >> 3);       // A rows, +8i (i=0..7)
    const int brow  = w * 16 + (lane >> 3);       // B rows, +8i (i=0..1)
    const int sxor  = (lane >> 3) & 7;            // == arow&7 == brow&7
    const int scol  = (lane & 7) * 8;
    const int sgcol = ((lane & 7) ^ sxor) * 8;
    const __bf16* Ap = Ablk + (long)arow * lda + sgcol;
    const __bf16* Bp = Bblk + (long)brow * ldb + sgcol;
    const int rx = n16 & 7;

    for (int k0 = 0; k0 < K; k0 += 64) {
#pragma unroll
        for (int i = 0; i < 8; i++)
            load_lds16(Ap + (long)i * 8 * lda + k0, &As[arow + i * 8][scol]);
#pragma unroll
        for (int i = 0; i < 2; i++)
            load_lds16(Bp + (long)i * 8 * ldb + k0, &Bs[brow + i * 8][scol]);
        __syncthreads();
        gemm_compute256(As, Bs, acc, wm, n16, quad, rx);
        __syncthreads();
    }
    gemm_epi256(acc, Cblk, ldc, wm, n16, quad);
}

template <typename OutT>
__device__ __forceinline__ void gemm25664_fb(__bf16 (&As)[256][64], __bf16 (&Bs)[64][64],
                                             const __bf16* __restrict__ Ablk,
                                             const float* __restrict__ Bblk,
                                             OutT* __restrict__ Cblk,
                                             int K, int lda, int ldb, int ldc) {
    const int tid  = threadIdx.x;
    const int lane = tid & 63;
    const int w    = tid >> 6;
    const int n16  = lane & 15;
    const int quad = lane >> 4;
    const int wm   = w * 64;

    f32x4 acc[4][4];
    const f32x4 fzero = {0.f, 0.f, 0.f, 0.f};
#pragma unroll
    for (int i = 0; i < 4; i++)
#pragma unroll
        for (int j = 0; j < 4; j++) acc[i][j] = fzero;

    const int arow  = w * 64 + (lane >> 3);
    const int sxor  = (lane >> 3) & 7;
    const int scol  = (lane & 7) * 8;
    const int sgcol = ((lane & 7) ^ sxor) * 8;
    const __bf16* Ap = Ablk + (long)arow * lda + sgcol;

    // B: one row per thread (64 rows x 64 fp32 cols = 16 consecutive floats
    // per thread), reg-staged, cvt->bf16, swizzled ds_write (2 chunks).
    const int brr  = tid >> 2;                    // B row 0..63
    const int bc0  = (tid & 3) * 16;              // first of 16 fp32 cols
    const int bch  = (tid & 3) * 2;               // first of 2 bf16x8 chunks
    const int bxor = brr & 7;
    const float* Bptr = Bblk + (long)brr * ldb + bc0;

    const int rx = n16 & 7;
    float4 breg[4];

#define LOAD_B(kk)                                                             \
    _Pragma("unroll") for (int i = 0; i < 4; i++)                              \
        breg[i] = *(const float4*)(Bptr + (kk) + i * 4);

    LOAD_B(0);
    for (int k0 = 0; k0 < K; k0 += 64) {
#pragma unroll
        for (int i = 0; i < 8; i++)
            load_lds16(Ap + (long)i * 8 * lda + k0, &As[arow + i * 8][scol]);
        {
            bf16x8 b0, b1;
#pragma unroll
            for (int j = 0; j < 4; j++) {
                b0[j]     = (__bf16)breg[0][j]; b0[j + 4] = (__bf16)breg[1][j];
                b1[j]     = (__bf16)breg[2][j]; b1[j + 4] = (__bf16)breg[3][j];
            }
            *(bf16x8*)&Bs[brr][((bch + 0) ^ bxor) * 8] = b0;
            *(bf16x8*)&Bs[brr][((bch + 1) ^ bxor) * 8] = b1;
        }
        if (k0 + 64 < K) LOAD_B(k0 + 64);   // in flight across compute below
        __syncthreads();
        gemm_compute256(As, Bs, acc, wm, n16, quad, rx);
        __syncthreads();
    }
#undef LOAD_B
    gemm_epi256(acc, Cblk, ldc, wm, n16, quad);
}

// ---------------------------------------------------------------------------
// Fused k + v + q projections, 640 blocks (all resident at 4/CU LDS cap).
// ---------------------------------------------------------------------------
__global__ __launch_bounds__(256, 4) void gemm_kvq(const __bf16* __restrict__ tgtb,
                                                   const __bf16* __restrict__ hidb,
                                                   const __bf16* __restrict__ wkb,
                                                   const __bf16* __restrict__ wvb,
                                                   const float* __restrict__ wq,
                                                   __bf16* __restrict__ kbf,
                                                   __bf16* __restrict__ vbf,
                                                   __bf16* __restrict__ qbf) {
    __shared__ __bf16 As[256][64];
    __shared__ __bf16 Bs[64][64];
    const int bid = blockIdx.x;
    const int b = (bid & 7) * 80 + (bid >> 3);    // bijective: 640 = 8*80
    if (b < 384) {
        const int z = b >= 192, t = b - z * 192;
        const int m0 = (t >> 4) * 256, n0 = (t & 15) * 64;
        const __bf16* Ap = (m0 < 2048) ? tgtb + (long)m0 * 2048
                                       : hidb + (long)(m0 - 2048) * 2048;
        const __bf16* Bp = (z ? wvb : wkb) + (long)n0 * 2048;
        __bf16* Cp = (z ? vbf : kbf) + (long)m0 * 1024 + n0;
        gemm25664_bb<__bf16>(As, Bs, Ap, Bp, Cp, 2048, 2048, 2048, 1024);
    } else {
        const int t = b - 384;
        const int m0 = (t >> 6) * 256, n0 = (t & 63) * 64;
        gemm25664_fb<__bf16>(As, Bs, hidb + (long)m0 * 2048, wq + (long)n0 * 2048,
                             qbf + (long)m0 * 4096 + n0, 2048, 2048, 2048, 4096);
    }
}

// ---------------------------------------------------------------------------
// Output projection: 256x64 tiles, split-K=4, B = fp32 wo direct (fb path).
// ---------------------------------------------------------------------------
__global__ __launch_bounds__(256, 4) void gemm_wo4(const __bf16* __restrict__ A,
                                                   const float* __restrict__ wo,
                                                   float* __restrict__ out,
                                                   float* __restrict__ p1,
                                                   float* __restrict__ p2,
                                                   float* __restrict__ p3) {
    __shared__ __bf16 As[256][64];
    __shared__ __bf16 Bs[64][64];
    const int bid = blockIdx.x;
    const int b = (bid & 7) * 64 + (bid >> 3);    // bijective: 512 = 8*64
    const int z = b >> 7, t = b & 127;            // 4m x 32n per z
    const int m0 = (t >> 5) * 256, n0 = (t & 31) * 64;
    float* C;
    switch (z) {
        case 0:  C = out; break;
        case 1:  C = p1;  break;
        case 2:  C = p2;  break;
        default: C = p3;  break;
    }
    gemm25664_fb<float>(As, Bs, A + (long)m0 * 4096 + z * 1024,
                        wo + (long)n0 * 4096 + z * 1024,
                        C + (long)m0 * 2048 + n0, 1024, 4096, 4096, 2048);
}

__global__ __launch_bounds__(256) void add4_wo(float* __restrict__ out,
                                               const float* __restrict__ p1,
                                               const float* __restrict__ p2,
                                               const float* __restrict__ p3, int n4) {
    int i = blockIdx.x * 256 + threadIdx.x;
    int stride = gridDim.x * 256;
    for (; i < n4; i += stride) {
        float4 a = ((const float4*)out)[i];
        float4 b = ((const float4*)p1)[i];
        float4 c = ((const float4*)p2)[i];
        float4 d = ((const float4*)p3)[i];
        float4 o;
        o.x = (a.x + b.x) + (c.x + d.x);
        o.y = (a.y + b.y) + (c.y + d.y);
        o.z = (a.z + b.z) + (c.z + d.z);
        o.w = (a.w + b.w) + (c.w + d.w);
        ((float4*)out)[i] = o;
    }
}

// ---------------------------------------------------------------------------
// Fused RMSNorm+RoPE for q (z=0) and k (z=1), in place.
// ---------------------------------------------------------------------------
__global__ __launch_bounds__(256) void rmsnorm_rope2(__bf16* __restrict__ xq,
                                                     const float* __restrict__ wq,
                                                     __bf16* __restrict__ xk,
                                                     const float* __restrict__ wk,
                                                     const float* __restrict__ cosb,
                                                     const float* __restrict__ sinb) {
    const int z = blockIdx.y;
    __bf16*      x = z ? xk : xq;
    const float* w = z ? wk : wq;
    const int nheads     = z ? 8 : 32;
    const int row_stride = z ? 1024 : 4096;
    const int pos_offset = z ? 0 : 2048;
    const float outscale = z ? 1.0f : 0.08838834764831845f;
    const int nitems     = z ? 3072 * 8 : 1024 * 32;

    int item = blockIdx.x * 4 + (threadIdx.x >> 6);
    int lane = threadIdx.x & 63;
    if (item >= nitems) return;
    int row = item / nheads;
    int head = item - row * nheads;
    __bf16* p = x + (long)row * row_stride + head * HD;

    float x1 = (float)p[lane], x2 = (float)p[lane + 64];
    float ss = x1 * x1 + x2 * x2;
#pragma unroll
    for (int o = 32; o >= 1; o >>= 1) ss += __shfl_xor(ss, o);
    float r = rsqrtf(ss * (1.0f / 128.0f) + 1e-6f) * outscale;

    int pos = pos_offset + row;
    float c1 = cosb[pos * HD + lane], c2 = cosb[pos * HD + lane + 64];
    float s1 = sinb[pos * HD + lane], s2 = sinb[pos * HD + lane + 64];
    float y1 = x1 * r * w[lane];
    float y2 = x2 * r * w[lane + 64];
    p[lane]      = (__bf16)(y1 * c1 - y2 * s1);
    p[lane + 64] = (__bf16)(y2 * c2 + y1 * s2);
}

// ---------------------------------------------------------------------------
// V transpose: vbf[t][g*128+d] -> vt[g][d][t]
// ---------------------------------------------------------------------------
__global__ __launch_bounds__(256) void transpose_v(const __bf16* __restrict__ v,
                                                   __bf16* __restrict__ vt) {
    __shared__ __bf16 T[64][68];
    const int tid = threadIdx.x;
    const int t0 = blockIdx.x * 64;
    const int d0 = blockIdx.y * 64;
    const int g  = blockIdx.z;
    const __bf16* src = v + (long)t0 * 1024 + g * 128 + d0;
#pragma unroll
    for (int i = 0; i < 4; i++) {
        int idx = tid + i * 256;
        int r = idx >> 4, c4 = (idx & 15) * 4;
        *(bf16x4*)&T[r][c4] = *(const bf16x4*)(src + (long)r * 1024 + c4);
    }
    __syncthreads();
    __bf16* dst = vt + (long)g * 128 * 3072 + (long)d0 * 3072 + t0;
#pragma unroll
    for (int i = 0; i < 4; i++) {
        int idx = tid + i * 256;
        int r = idx >> 4, c4 = (idx & 15) * 4;
        bf16x4 o;
        o[0] = T[c4 + 0][r]; o[1] = T[c4 + 1][r];
        o[2] = T[c4 + 2][r]; o[3] = T[c4 + 3][r];
        *(bf16x4*)(dst + (long)r * 3072 + c4) = o;
    }
}

// ---------------------------------------------------------------------------
// Split-K flash attention. R13/R14 (from R12 counters: MfmaUtil 22.7 / VALU
// 32.7 / Occ 15.7 / conflicts 11% -> barrier-latency + LDS-pipe bound at
// 2 blocks/CU):
//  (1) Ps gets its OWN LDS (was aliasing Ks) -> the mid-loop barrier drops;
//      2 barriers/tile-step. LDS 35840 -> 53248 B, still 3 blocks/CU.
//  (2) T14 prefetch: next tile's K/V global->reg loads issue during compute;
//      reg->LDS write lands between end-barrier and next stage-ready barrier.
//  (3) 3-way split-K (768 blocks = 3/CU, launch_bounds(256,3)); fixed-shift
//      softmax makes any t-partition additively mergeable.
// R14 = R13 resubmit (container failure was infra-side; race/bounds/overlay/
// occupancy audit clean — same precedent as R11->R12).
// ---------------------------------------------------------------------------
__global__ __launch_bounds__(256, 3) void flash_attn_splitk(const __bf16* __restrict__ qb,
                                                            const __bf16* __restrict__ kb,
                                                            const __bf16* __restrict__ vtg,
                                                            __bf16* __restrict__ Opart0,
                                                            __bf16* __restrict__ Opart1,
                                                            __bf16* __restrict__ Opart2,
                                                            float* __restrict__ lsum) {
    __shared__ __bf16 KsU[64 * 136];   // Ks[t][d] stride 136 (17408 B)
    __shared__ __bf16 Vs[128][72];     // [d][t]              (18432 B)
    __shared__ __bf16 PsU[4 * 32 * 68];// per-wave P tiles    (17408 B)
#define KS(r, c) KsU[(r) * 136 + (c)]
#define PS(w_, m_, t_) PsU[(w_) * 2176 + (m_) * 68 + (t_)]

    const int tid  = threadIdx.x;
    const int lane = tid & 63;
    const int w    = tid >> 6;
    const int n    = lane & 15;
    const int quad = lane >> 4;

    const int bid = blockIdx.x;        // 0..255
    const int s   = blockIdx.y;        // 0..2
    const int g  = bid & 7;
    const int jj = bid >> 3;           // 0..31
    const int h  = g * 4 + (jj & 3);
    const int qt = jj >> 2;            // 0..7, 128-row q tiles

    const int qr0 = qt * 128 + w * 16; // m-tile 0 base; m-tile 1 = +64

    bf16x8 qf[2][4];
#pragma unroll
    for (int mt = 0; mt < 2; mt++) {
        const __bf16* qp = qb + (long)(qr0 + mt * 64 + n) * 4096 + h * 128 + quad * 8;
        qf[mt][0] = *(const bf16x8*)(qp);
        qf[mt][1] = *(const bf16x8*)(qp + 32);
        qf[mt][2] = *(const bf16x8*)(qp + 64);
        qf[mt][3] = *(const bf16x8*)(qp + 96);
    }

    f32x4 O[2][8];
    const f32x4 fzero = {0.f, 0.f, 0.f, 0.f};
#pragma unroll
    for (int mt = 0; mt < 2; mt++)
#pragma unroll
        for (int dt = 0; dt < 8; dt++) O[mt][dt] = fzero;
    float l_loc[2] = {0.f, 0.f};       // lane-local: lane n16 owns q-row qr0+mt*64+n

    const int ntot = 34 + 2 * qt;
    const int tbeg = (s * ntot) / 3;
    const int tend = ((s + 1) * ntot) / 3;

    const int krr = tid >> 4, kc8 = (tid & 15) * 8;
    const int vrr = tid >> 3, vc8 = (tid & 7) * 8;
    const __bf16* kp = kb + g * 128 + (long)(tbeg * 64 + krr) * 1024 + kc8;
    const __bf16* vp = vtg + (long)g * 128 * 3072 + (long)vrr * 3072 + tbeg * 64 + vc8;

    bf16x8 kreg[4], vreg[4];
#define LOADKV()                                                               \
    do {                                                                       \
        _Pragma("unroll") for (int i = 0; i < 4; i++) {                        \
            kreg[i] = *(const bf16x8*)(kp + (long)i * 16 * 1024);              \
            vreg[i] = *(const bf16x8*)(vp + (long)i * 32 * 3072);              \
        }                                                                      \
        kp += 64 * 1024;                                                       \
        vp += 64;                                                              \
    } while (0)
#define WRITEKV()                                                              \
    do {                                                                       \
        _Pragma("unroll") for (int i = 0; i < 4; i++) {                        \
            *(bf16x8*)&KS(krr + i * 16, kc8) = kreg[i];                        \
            *(bf16x8*)&Vs[vrr + i * 32][vc8] = vreg[i];                        \
        }                                                                      \
    } while (0)

    // prologue: tile tbeg staged; tile tbeg+1 loads in flight
    LOADKV();
    WRITEKV();
    if (tbeg + 1 < tend) LOADKV();

    for (int tt = tbeg; tt < tend; tt++) {
        __syncthreads();   // staged K/V tile visible to all waves

        // S^T = K Q^T: A = K-frag, B = Q-frag (identical lane layouts).
        // Result: col(lane&15) = q-row, row(quad*4+r) = key t.
        f32x4 S[2][4];
#pragma unroll
        for (int nt = 0; nt < 4; nt++) {
            f32x4 a0 = fzero, a1 = fzero;
#pragma unroll
            for (int ks = 0; ks < 4; ks++) {
                bf16x8 kf = *(const bf16x8*)&KS(nt * 16 + n, ks * 32 + quad * 8);
                a0 = MFMA16(kf, qf[0][ks], a0);
                a1 = MFMA16(kf, qf[1][ks], a1);
            }
            S[0][nt] = a0;
            S[1][nt] = a1;
        }

        if (tt >= ntot - 2) {   // diagonal band spans the last two tiles
            const int t0 = tt * 64;
#pragma unroll
            for (int mt = 0; mt < 2; mt++) {
                const int lim = 2048 + qr0 + mt * 64 + n;   // q-row = lane index
#pragma unroll
                for (int nt = 0; nt < 4; nt++)
#pragma unroll
                    for (int r = 0; r < 4; r++) {
                        int t = t0 + nt * 16 + quad * 4 + r;
                        if (t > lim) S[mt][nt][r] = -1e30f;
                    }
            }
        }

        // fixed-shift softmax; row-sum is lane-local (lane owns its q-row)
#pragma unroll
        for (int mt = 0; mt < 2; mt++)
#pragma unroll
            for (int nt = 0; nt < 4; nt++)
#pragma unroll
                for (int r = 0; r < 4; r++) {
                    float p = __expf(S[mt][nt][r] - MSTATIC);
                    S[mt][nt][r] = p;
                    l_loc[mt] += p;
                }

        // P -> LDS (per-wave private region; same-wave DS ordering suffices)
#pragma unroll
        for (int mt = 0; mt < 2; mt++)
#pragma unroll
            for (int nt = 0; nt < 4; nt++) {
                bf16x4 pk;
#pragma unroll
                for (int r = 0; r < 4; r++) pk[r] = (__bf16)S[mt][nt][r];
                *(bf16x4*)&PS(w, mt * 16 + n, nt * 16 + quad * 4) = pk;
            }

        bf16x8 pa[2][2];
#pragma unroll
        for (int mt = 0; mt < 2; mt++)
#pragma unroll
            for (int kg = 0; kg < 2; kg++)
                pa[mt][kg] = *(const bf16x8*)&PS(w, mt * 16 + n, kg * 32 + quad * 8);

#pragma unroll
        for (int dt = 0; dt < 8; dt++) {
            bf16x8 vf0 = *(const bf16x8*)&Vs[dt * 16 + n][quad * 8];
            bf16x8 vf1 = *(const bf16x8*)&Vs[dt * 16 + n][32 + quad * 8];
#pragma unroll
            for (int mt = 0; mt < 2; mt++) {
                f32x4 acc = O[mt][dt];
                acc = MFMA16(pa[mt][0], vf0, acc);
                acc = MFMA16(pa[mt][1], vf1, acc);
                O[mt][dt] = acc;
            }
        }

        __syncthreads();   // all Ks/Vs reads done; next tile may be written
        if (tt + 1 < tend) {
            WRITEKV();                    // regs hold tile tt+1
            if (tt + 2 < tend) LOADKV();  // issue loads for tile tt+2
        }
    }
#undef LOADKV
#undef WRITEKV

    // row-sum: reduce across the 4 quads (lane already holds its row's partial)
#pragma unroll
    for (int mt = 0; mt < 2; mt++) {
        float sm = l_loc[mt];
        sm += __shfl_xor(sm, 16);
        sm += __shfl_xor(sm, 32);
        l_loc[mt] = sm;
    }

    __bf16* Op = (s == 0) ? Opart0 : (s == 1 ? Opart1 : Opart2);
    const long tb = (long)(h * 8 + qt) * 128 * 128;
#pragma unroll
    for (int mt = 0; mt < 2; mt++)
#pragma unroll
        for (int dt = 0; dt < 8; dt++)
#pragma unroll
            for (int r = 0; r < 4; r++)
                Op[tb + (long)(mt * 64 + w * 16 + quad * 4 + r) * 128 + dt * 16 + n] =
                    (__bf16)O[mt][dt][r];
    if (quad == 0) {
        const int lb = (s * 256 + h * 8 + qt) * 128 + w * 16;
#pragma unroll
        for (int mt = 0; mt < 2; mt++)
            lsum[lb + mt * 64 + n] = l_loc[mt];
    }
#undef KS
#undef PS
}

// ---------------------------------------------------------------------------
// Additive merge of 3 split-K partials -> normalized bf16 attn-out.
// ---------------------------------------------------------------------------
__global__ __launch_bounds__(256) void flash_merge(const __bf16* __restrict__ O0,
                                                   const __bf16* __restrict__ O1,
                                                   const __bf16* __restrict__ O2,
                                                   const float* __restrict__ lsum,
                                                   __bf16* __restrict__ ob) {
    const int bx = blockIdx.x;         // 512: (h, qt, half64)
    const int h   = bx >> 4;
    const int r6  = bx & 15;
    const int qt  = r6 >> 1;
    const int sub = r6 & 1;
    const int row  = threadIdx.x >> 2;
    const int cseg = (threadIdx.x & 3) * 32;
    const int mrow = sub * 64 + row;

    const int tilei = h * 8 + qt;
    float inv = 1.0f / (lsum[tilei * 128 + mrow] + lsum[(256 + tilei) * 128 + mrow] +
                        lsum[(512 + tilei) * 128 + mrow]);

    const long src = (long)tilei * 128 * 128 + (long)mrow * 128 + cseg;
    __bf16* dst = ob + (long)(qt * 128 + mrow) * 4096 + h * 128 + cseg;
#pragma unroll
    for (int j = 0; j < 4; j++) {
        bf16x8 x0 = *(const bf16x8*)(O0 + src + j * 8);
        bf16x8 x1 = *(const bf16x8*)(O1 + src + j * 8);
        bf16x8 x2 = *(const bf16x8*)(O2 + src + j * 8);
        bf16x8 o;
#pragma unroll
        for (int k = 0; k < 8; k++)
            o[k] = (__bf16)((((float)x0[k] + (float)x1[k]) + (float)x2[k]) * inv);
        *(bf16x8*)(dst + j * 8) = o;
    }
}

// ---------------------------------------------------------------------------
extern "C" void kernel_launch(void* const* d_in, const int* in_sizes, int n_in,
                              void* d_out, int out_size, void* d_ws, size_t ws_size,
                              hipStream_t stream) {
    const float* hidden = (const float*)d_in[0];
    const float* target = (const float*)d_in[1];
    const float* cosb   = (const float*)d_in[2];
    const float* sinb   = (const float*)d_in[3];
    const float* wq = (const float*)d_in[5];
    const float* wk = (const float*)d_in[6];
    const float* wv = (const float*)d_in[7];
    const float* wo = (const float*)d_in[8];
    const float* qw = (const float*)d_in[9];
    const float* kw = (const float*)d_in[10];
    float* out = (float*)d_out;

    // 40 MB workspace overlays (launch order guarantees safety). Layout for
    // 3 flash partials (24 MB):
    //   phase A (conv/kvq):   kbf@0-6  vbf@12-18
    //                         hidb@20-24 tgtb@24-32 wkb@32-36 wvb@36-40
    //   phase A2 (transpose): vtg@6-12
    //   phase B (flash):      reads kbf@0-6, vtg@6-12, qbf(d_out)
    //                         writes Op0@12-20 Op1@20-28 Op2@28-36 lbuf@36-36.4
    //   phase C (merge):      writes attnb@0-8
    //   phase D (wo4/add4):   po1@8-16 po2@16-24 po3@24-32, out=d_out
    char* ws = (char*)d_ws;
    const long MB = 1 << 20;
    __bf16* kbf  = (__bf16*)(ws);             // @0..6
    __bf16* vtg  = (__bf16*)(ws + 6 * MB);    // @6..12
    __bf16* vbf  = (__bf16*)(ws + 12 * MB);   // @12..18
    __bf16* hidb = (__bf16*)(ws + 20 * MB);   // @20..24
    __bf16* tgtb = (__bf16*)(ws + 24 * MB);   // @24..32
    __bf16* wkb  = (__bf16*)(ws + 32 * MB);   // @32..36
    __bf16* wvb  = (__bf16*)(ws + 36 * MB);   // @36..40
    __bf16* Op0  = (__bf16*)(ws + 12 * MB);   // @12..20 (post-transpose)
    __bf16* Op1  = (__bf16*)(ws + 20 * MB);   // @20..28 (post-kvq)
    __bf16* Op2  = (__bf16*)(ws + 28 * MB);   // @28..36 (post-kvq)
    float*  lbuf = (float*)(ws + 36 * MB);    // @36..36.4 (post-kvq)
    __bf16* attnb= (__bf16*)(ws);             // @0..8   (post-flash)
    float*  po1  = (float*)(ws + 8 * MB);     // @8..16  (post-merge)
    float*  po2  = (float*)(ws + 16 * MB);    // @16..24 (post-merge)
    float*  po3  = (float*)(ws + 24 * MB);    // @24..32 (post-merge)
    __bf16* qbf  = (__bf16*)d_out;            // 8MB: q / dead after flash

    dim3 blk(256);

    // activations + k/v weights -> bf16
    conv4_f32_bf16<<<dim3(1024, 4), blk, 0, stream>>>(
        hidden, hidb, (1024 * 2048) / 4, target, tgtb, (2048 * 2048) / 4,
        wk, wkb, (1024 * 2048) / 4, wv, wvb, (1024 * 2048) / 4);

    // all three projections, one launch, 640 blocks all resident
    gemm_kvq<<<640, blk, 0, stream>>>(tgtb, hidb, wkb, wvb, wq, kbf, vbf, qbf);

    // fused RMSNorm + RoPE (q and k)
    rmsnorm_rope2<<<dim3(8192, 2), blk, 0, stream>>>(qbf, qw, kbf, kw, cosb, sinb);

    // V transpose -> [g][d][t]
    transpose_v<<<dim3(48, 2, 8), blk, 0, stream>>>(vbf, vtg);

    // 3-way split-K flash attention (768 blocks = 3/CU) + additive merge
    flash_attn_splitk<<<dim3(256, 3), blk, 0, stream>>>(qbf, kbf, vtg,
                                                        Op0, Op1, Op2, lbuf);
    flash_merge<<<512, blk, 0, stream>>>(Op0, Op1, Op2, lbuf, attnb);

    // output projection: 256x64 fb tiles, split-K=4 (512 blocks) + reduce
    gemm_wo4<<<512, blk, 0, stream>>>(attnb, wo, out, po1, po2, po3);
    add4_wo<<<1024, blk, 0, stream>>>(out, po1, po2, po3, (1024 * 2048) / 4);
}

// Round 8
// 362.391 us; speedup vs baseline: 1.0323x; 1.0323x over previous
//
#include <hip/hip_runtime.h>

#define HIDDEN 2048
#define NQ     1024
#define NCTX   2048
#define NTOT   3072
#define NHEADS 32
#define KVH    8
#define HD     128

typedef __attribute__((ext_vector_type(8))) __bf16 bf16x8;
typedef __attribute__((ext_vector_type(4))) __bf16 bf16x4;
typedef __attribute__((ext_vector_type(4))) float  f32x4;

#define MFMA16(a, b, c) __builtin_amdgcn_mfma_f32_16x16x32_bf16(a, b, c, 0, 0, 0)

// Fixed softmax shift (Cauchy-Schwarz: |q|=1 after folded 1/sqrt(d), |k|=sqrt(128),
// RoPE norm-preserving => s <= 11.4 incl. bf16 rounding).
#define MSTATIC 12.0f

__device__ __forceinline__ void load_lds16(const void* g, void* l) {
    __builtin_amdgcn_global_load_lds(
        (const __attribute__((address_space(1))) unsigned int*)g,
        (__attribute__((address_space(3))) unsigned int*)l, 16, 0, 0);
}

// ---------------------------------------------------------------------------
// 4-way fused fp32 -> bf16 convert (activations + k/v weights)
// ---------------------------------------------------------------------------
__global__ __launch_bounds__(256) void conv4_f32_bf16(const float* __restrict__ s0,
                                                      __bf16* __restrict__ d0, int n0,
                                                      const float* __restrict__ s1,
                                                      __bf16* __restrict__ d1, int n1,
                                                      const float* __restrict__ s2,
                                                      __bf16* __restrict__ d2, int n2,
                                                      const float* __restrict__ s3,
                                                      __bf16* __restrict__ d3, int n3) {
    const float* s; __bf16* d; int n;
    switch (blockIdx.y) {
        case 0:  s = s0; d = d0; n = n0; break;
        case 1:  s = s1; d = d1; n = n1; break;
        case 2:  s = s2; d = d2; n = n2; break;
        default: s = s3; d = d3; n = n3; break;
    }
    int i = blockIdx.x * 256 + threadIdx.x;
    int stride = gridDim.x * 256;
    for (; i < n; i += stride) {
        float4 v = ((const float4*)s)[i];
        bf16x4 o;
        o[0] = (__bf16)v.x; o[1] = (__bf16)v.y;
        o[2] = (__bf16)v.z; o[3] = (__bf16)v.w;
        ((bf16x4*)d)[i] = o;
    }
}

// ---------------------------------------------------------------------------
// 256x64 MFMA GEMM tile bodies (R11-verified: delivery-bound fix, 9.8 B/KFLOP).
// XOR bank-swizzle (R8-verified): linear LDS dest + pre-swizzled global source
// + swizzled read.
//   bb: both operands bf16, pure async global->LDS staging (zero VALU).
//   fb: A bf16 async; B fp32 reg-staged one K-step ahead (T14), cvt->LDS.
// ---------------------------------------------------------------------------
__device__ __forceinline__ void gemm_compute256(const __bf16 (&As)[256][64],
                                                const __bf16 (&Bs)[64][64],
                                                f32x4 (&acc)[4][4],
                                                int wm, int n16, int quad, int rx) {
#pragma unroll
    for (int ks = 0; ks < 2; ks++) {
        bf16x8 af[4], bfr[4];
#pragma unroll
        for (int i = 0; i < 4; i++)
            af[i] = *(const bf16x8*)&As[wm + i * 16 + n16][((ks * 4 + quad) ^ rx) * 8];
#pragma unroll
        for (int j = 0; j < 4; j++)
            bfr[j] = *(const bf16x8*)&Bs[j * 16 + n16][((ks * 4 + quad) ^ rx) * 8];
#pragma unroll
        for (int i = 0; i < 4; i++)
#pragma unroll
            for (int j = 0; j < 4; j++)
                acc[i][j] = MFMA16(af[i], bfr[j], acc[i][j]);
    }
}

template <typename OutT>
__device__ __forceinline__ void gemm_epi256(const f32x4 (&acc)[4][4],
                                            OutT* __restrict__ Cblk, int ldc,
                                            int wm, int n16, int quad) {
#pragma unroll
    for (int i = 0; i < 4; i++)
#pragma unroll
        for (int j = 0; j < 4; j++)
#pragma unroll
            for (int r = 0; r < 4; r++)
                Cblk[(long)(wm + i * 16 + quad * 4 + r) * ldc + j * 16 + n16] =
                    (OutT)acc[i][j][r];
}

template <typename OutT>
__device__ __forceinline__ void gemm25664_bb(__bf16 (&As)[256][64], __bf16 (&Bs)[64][64],
                                             const __bf16* __restrict__ Ablk,
                                             const __bf16* __restrict__ Bblk,
                                             OutT* __restrict__ Cblk,
                                             int K, int lda, int ldb, int ldc) {
    const int tid  = threadIdx.x;
    const int lane = tid & 63;
    const int w    = tid >> 6;
    const int n16  = lane & 15;
    const int quad = lane >> 4;
    const int wm   = w * 64;                      // wave's 64-row m-slab

    f32x4 acc[4][4];
    const f32x4 fzero = {0.f, 0.f, 0.f, 0.f};
#pragma unroll
    for (int i = 0; i < 4; i++)
#pragma unroll
        for (int j = 0; j < 4; j++) acc[i][j] = fzero;

    // Linear LDS dest (gload_lds: wave-uniform base + lane*16); source col
    // pre-XORed so LDS[r][chunk c] holds global chunk c^(r&7).
    const int arow  = w * 64 + (lane >> 3);       // A rows, +8i (i=0..7)
    const int brow  = w * 16 + (lane >> 3);       // B rows, +8i (i=0..1)
    const int sxor  = (lane >> 3) & 7;            // == arow&7 == brow&7
    const int scol  = (lane & 7) * 8;
    const int sgcol = ((lane & 7) ^ sxor) * 8;
    const __bf16* Ap = Ablk + (long)arow * lda + sgcol;
    const __bf16* Bp = Bblk + (long)brow * ldb + sgcol;
    const int rx = n16 & 7;

    for (int k0 = 0; k0 < K; k0 += 64) {
#pragma unroll
        for (int i = 0; i < 8; i++)
            load_lds16(Ap + (long)i * 8 * lda + k0, &As[arow + i * 8][scol]);
#pragma unroll
        for (int i = 0; i < 2; i++)
            load_lds16(Bp + (long)i * 8 * ldb + k0, &Bs[brow + i * 8][scol]);
        __syncthreads();
        gemm_compute256(As, Bs, acc, wm, n16, quad, rx);
        __syncthreads();
    }
    gemm_epi256(acc, Cblk, ldc, wm, n16, quad);
}

template <typename OutT>
__device__ __forceinline__ void gemm25664_fb(__bf16 (&As)[256][64], __bf16 (&Bs)[64][64],
                                             const __bf16* __restrict__ Ablk,
                                             const float* __restrict__ Bblk,
                                             OutT* __restrict__ Cblk,
                                             int K, int lda, int ldb, int ldc) {
    const int tid  = threadIdx.x;
    const int lane = tid & 63;
    const int w    = tid >> 6;
    const int n16  = lane & 15;
    const int quad = lane >> 4;
    const int wm   = w * 64;

    f32x4 acc[4][4];
    const f32x4 fzero = {0.f, 0.f, 0.f, 0.f};
#pragma unroll
    for (int i = 0; i < 4; i++)
#pragma unroll
        for (int j = 0; j < 4; j++) acc[i][j] = fzero;

    const int arow  = w * 64 + (lane >> 3);
    const int sxor  = (lane >> 3) & 7;
    const int scol  = (lane & 7) * 8;
    const int sgcol = ((lane & 7) ^ sxor) * 8;
    const __bf16* Ap = Ablk + (long)arow * lda + sgcol;

    // B: one row per thread (64 rows x 64 fp32 cols = 16 consecutive floats
    // per thread), reg-staged, cvt->bf16, swizzled ds_write (2 chunks).
    const int brr  = tid >> 2;                    // B row 0..63
    const int bc0  = (tid & 3) * 16;              // first of 16 fp32 cols
    const int bch  = (tid & 3) * 2;               // first of 2 bf16x8 chunks
    const int bxor = brr & 7;
    const float* Bptr = Bblk + (long)brr * ldb + bc0;

    const int rx = n16 & 7;
    float4 breg[4];

#define LOAD_B(kk)                                                             \
    _Pragma("unroll") for (int i = 0; i < 4; i++)                              \
        breg[i] = *(const float4*)(Bptr + (kk) + i * 4);

    LOAD_B(0);
    for (int k0 = 0; k0 < K; k0 += 64) {
#pragma unroll
        for (int i = 0; i < 8; i++)
            load_lds16(Ap + (long)i * 8 * lda + k0, &As[arow + i * 8][scol]);
        {
            bf16x8 b0, b1;
#pragma unroll
            for (int j = 0; j < 4; j++) {
                b0[j]     = (__bf16)breg[0][j]; b0[j + 4] = (__bf16)breg[1][j];
                b1[j]     = (__bf16)breg[2][j]; b1[j + 4] = (__bf16)breg[3][j];
            }
            *(bf16x8*)&Bs[brr][((bch + 0) ^ bxor) * 8] = b0;
            *(bf16x8*)&Bs[brr][((bch + 1) ^ bxor) * 8] = b1;
        }
        if (k0 + 64 < K) LOAD_B(k0 + 64);   // in flight across compute below
        __syncthreads();
        gemm_compute256(As, Bs, acc, wm, n16, quad, rx);
        __syncthreads();
    }
#undef LOAD_B
    gemm_epi256(acc, Cblk, ldc, wm, n16, quad);
}

// ---------------------------------------------------------------------------
// Fused k + v + q projections, 640 blocks (all resident at 4/CU LDS cap).
// ---------------------------------------------------------------------------
__global__ __launch_bounds__(256, 4) void gemm_kvq(const __bf16* __restrict__ tgtb,
                                                   const __bf16* __restrict__ hidb,
                                                   const __bf16* __restrict__ wkb,
                                                   const __bf16* __restrict__ wvb,
                                                   const float* __restrict__ wq,
                                                   __bf16* __restrict__ kbf,
                                                   __bf16* __restrict__ vbf,
                                                   __bf16* __restrict__ qbf) {
    __shared__ __bf16 As[256][64];
    __shared__ __bf16 Bs[64][64];
    const int bid = blockIdx.x;
    const int b = (bid & 7) * 80 + (bid >> 3);    // bijective: 640 = 8*80
    if (b < 384) {
        const int z = b >= 192, t = b - z * 192;
        const int m0 = (t >> 4) * 256, n0 = (t & 15) * 64;
        const __bf16* Ap = (m0 < 2048) ? tgtb + (long)m0 * 2048
                                       : hidb + (long)(m0 - 2048) * 2048;
        const __bf16* Bp = (z ? wvb : wkb) + (long)n0 * 2048;
        __bf16* Cp = (z ? vbf : kbf) + (long)m0 * 1024 + n0;
        gemm25664_bb<__bf16>(As, Bs, Ap, Bp, Cp, 2048, 2048, 2048, 1024);
    } else {
        const int t = b - 384;
        const int m0 = (t >> 6) * 256, n0 = (t & 63) * 64;
        gemm25664_fb<__bf16>(As, Bs, hidb + (long)m0 * 2048, wq + (long)n0 * 2048,
                             qbf + (long)m0 * 4096 + n0, 2048, 2048, 2048, 4096);
    }
}

// ---------------------------------------------------------------------------
// Output projection: 256x64 tiles, split-K=4, B = fp32 wo direct (fb path).
// ---------------------------------------------------------------------------
__global__ __launch_bounds__(256, 4) void gemm_wo4(const __bf16* __restrict__ A,
                                                   const float* __restrict__ wo,
                                                   float* __restrict__ out,
                                                   float* __restrict__ p1,
                                                   float* __restrict__ p2,
                                                   float* __restrict__ p3) {
    __shared__ __bf16 As[256][64];
    __shared__ __bf16 Bs[64][64];
    const int bid = blockIdx.x;
    const int b = (bid & 7) * 64 + (bid >> 3);    // bijective: 512 = 8*64
    const int z = b >> 7, t = b & 127;            // 4m x 32n per z
    const int m0 = (t >> 5) * 256, n0 = (t & 31) * 64;
    float* C;
    switch (z) {
        case 0:  C = out; break;
        case 1:  C = p1;  break;
        case 2:  C = p2;  break;
        default: C = p3;  break;
    }
    gemm25664_fb<float>(As, Bs, A + (long)m0 * 4096 + z * 1024,
                        wo + (long)n0 * 4096 + z * 1024,
                        C + (long)m0 * 2048 + n0, 1024, 4096, 4096, 2048);
}

__global__ __launch_bounds__(256) void add4_wo(float* __restrict__ out,
                                               const float* __restrict__ p1,
                                               const float* __restrict__ p2,
                                               const float* __restrict__ p3, int n4) {
    int i = blockIdx.x * 256 + threadIdx.x;
    int stride = gridDim.x * 256;
    for (; i < n4; i += stride) {
        float4 a = ((const float4*)out)[i];
        float4 b = ((const float4*)p1)[i];
        float4 c = ((const float4*)p2)[i];
        float4 d = ((const float4*)p3)[i];
        float4 o;
        o.x = (a.x + b.x) + (c.x + d.x);
        o.y = (a.y + b.y) + (c.y + d.y);
        o.z = (a.z + b.z) + (c.z + d.z);
        o.w = (a.w + b.w) + (c.w + d.w);
        ((float4*)out)[i] = o;
    }
}

// ---------------------------------------------------------------------------
// Fused RMSNorm+RoPE for q (z=0) and k (z=1), in place.
// ---------------------------------------------------------------------------
__global__ __launch_bounds__(256) void rmsnorm_rope2(__bf16* __restrict__ xq,
                                                     const float* __restrict__ wq,
                                                     __bf16* __restrict__ xk,
                                                     const float* __restrict__ wk,
                                                     const float* __restrict__ cosb,
                                                     const float* __restrict__ sinb) {
    const int z = blockIdx.y;
    __bf16*      x = z ? xk : xq;
    const float* w = z ? wk : wq;
    const int nheads     = z ? 8 : 32;
    const int row_stride = z ? 1024 : 4096;
    const int pos_offset = z ? 0 : 2048;
    const float outscale = z ? 1.0f : 0.08838834764831845f;
    const int nitems     = z ? 3072 * 8 : 1024 * 32;

    int item = blockIdx.x * 4 + (threadIdx.x >> 6);
    int lane = threadIdx.x & 63;
    if (item >= nitems) return;
    int row = item / nheads;
    int head = item - row * nheads;
    __bf16* p = x + (long)row * row_stride + head * HD;

    float x1 = (float)p[lane], x2 = (float)p[lane + 64];
    float ss = x1 * x1 + x2 * x2;
#pragma unroll
    for (int o = 32; o >= 1; o >>= 1) ss += __shfl_xor(ss, o);
    float r = rsqrtf(ss * (1.0f / 128.0f) + 1e-6f) * outscale;

    int pos = pos_offset + row;
    float c1 = cosb[pos * HD + lane], c2 = cosb[pos * HD + lane + 64];
    float s1 = sinb[pos * HD + lane], s2 = sinb[pos * HD + lane + 64];
    float y1 = x1 * r * w[lane];
    float y2 = x2 * r * w[lane + 64];
    p[lane]      = (__bf16)(y1 * c1 - y2 * s1);
    p[lane + 64] = (__bf16)(y2 * c2 + y1 * s2);
}

// ---------------------------------------------------------------------------
// V transpose: vbf[t][g*128+d] -> vt[g][d][t]
// ---------------------------------------------------------------------------
__global__ __launch_bounds__(256) void transpose_v(const __bf16* __restrict__ v,
                                                   __bf16* __restrict__ vt) {
    __shared__ __bf16 T[64][68];
    const int tid = threadIdx.x;
    const int t0 = blockIdx.x * 64;
    const int d0 = blockIdx.y * 64;
    const int g  = blockIdx.z;
    const __bf16* src = v + (long)t0 * 1024 + g * 128 + d0;
#pragma unroll
    for (int i = 0; i < 4; i++) {
        int idx = tid + i * 256;
        int r = idx >> 4, c4 = (idx & 15) * 4;
        *(bf16x4*)&T[r][c4] = *(const bf16x4*)(src + (long)r * 1024 + c4);
    }
    __syncthreads();
    __bf16* dst = vt + (long)g * 128 * 3072 + (long)d0 * 3072 + t0;
#pragma unroll
    for (int i = 0; i < 4; i++) {
        int idx = tid + i * 256;
        int r = idx >> 4, c4 = (idx & 15) * 4;
        bf16x4 o;
        o[0] = T[c4 + 0][r]; o[1] = T[c4 + 1][r];
        o[2] = T[c4 + 2][r]; o[3] = T[c4 + 3][r];
        *(bf16x4*)(dst + (long)r * 3072 + c4) = o;
    }
}

// ---------------------------------------------------------------------------
// Split-K flash attention. R15: R14's counters showed launch_bounds(256,3)
// clamped the allocator to 84 VGPR (demand ~106+) -> per-step scratch spills
// -> WRITE_SIZE 16.6 -> 233 MB, dur 78 -> 110. Fix: PLAIN launch_bounds(256)
// (the R12 binding that allocated 120 VGPR spill-free); LDS 53248 B still
// caps residency at 3 blocks/CU. Structure otherwise = R13 (all verified
// innocent by the R14 counters: own Ps buffer -> 2 barriers/step; T14 K/V
// prefetch; 3-way split-K, fixed-shift softmax additively mergeable).
// ---------------------------------------------------------------------------
__global__ __launch_bounds__(256) void flash_attn_splitk(const __bf16* __restrict__ qb,
                                                         const __bf16* __restrict__ kb,
                                                         const __bf16* __restrict__ vtg,
                                                         __bf16* __restrict__ Opart0,
                                                         __bf16* __restrict__ Opart1,
                                                         __bf16* __restrict__ Opart2,
                                                         float* __restrict__ lsum) {
    __shared__ __bf16 KsU[64 * 136];   // Ks[t][d] stride 136 (17408 B)
    __shared__ __bf16 Vs[128][72];     // [d][t]              (18432 B)
    __shared__ __bf16 PsU[4 * 32 * 68];// per-wave P tiles    (17408 B)
#define KS(r, c) KsU[(r) * 136 + (c)]
#define PS(w_, m_, t_) PsU[(w_) * 2176 + (m_) * 68 + (t_)]

    const int tid  = threadIdx.x;
    const int lane = tid & 63;
    const int w    = tid >> 6;
    const int n    = lane & 15;
    const int quad = lane >> 4;

    const int bid = blockIdx.x;        // 0..255
    const int s   = blockIdx.y;        // 0..2
    const int g  = bid & 7;
    const int jj = bid >> 3;           // 0..31
    const int h  = g * 4 + (jj & 3);
    const int qt = jj >> 2;            // 0..7, 128-row q tiles

    const int qr0 = qt * 128 + w * 16; // m-tile 0 base; m-tile 1 = +64

    bf16x8 qf[2][4];
#pragma unroll
    for (int mt = 0; mt < 2; mt++) {
        const __bf16* qp = qb + (long)(qr0 + mt * 64 + n) * 4096 + h * 128 + quad * 8;
        qf[mt][0] = *(const bf16x8*)(qp);
        qf[mt][1] = *(const bf16x8*)(qp + 32);
        qf[mt][2] = *(const bf16x8*)(qp + 64);
        qf[mt][3] = *(const bf16x8*)(qp + 96);
    }

    f32x4 O[2][8];
    const f32x4 fzero = {0.f, 0.f, 0.f, 0.f};
#pragma unroll
    for (int mt = 0; mt < 2; mt++)
#pragma unroll
        for (int dt = 0; dt < 8; dt++) O[mt][dt] = fzero;
    float l_loc[2] = {0.f, 0.f};       // lane-local: lane n16 owns q-row qr0+mt*64+n

    const int ntot = 34 + 2 * qt;
    const int tbeg = (s * ntot) / 3;
    const int tend = ((s + 1) * ntot) / 3;

    const int krr = tid >> 4, kc8 = (tid & 15) * 8;
    const int vrr = tid >> 3, vc8 = (tid & 7) * 8;
    const __bf16* kp = kb + g * 128 + (long)(tbeg * 64 + krr) * 1024 + kc8;
    const __bf16* vp = vtg + (long)g * 128 * 3072 + (long)vrr * 3072 + tbeg * 64 + vc8;

    bf16x8 kreg[4], vreg[4];
#define LOADKV()                                                               \
    do {                                                                       \
        _Pragma("unroll") for (int i = 0; i < 4; i++) {                        \
            kreg[i] = *(const bf16x8*)(kp + (long)i * 16 * 1024);              \
            vreg[i] = *(const bf16x8*)(vp + (long)i * 32 * 3072);              \
        }                                                                      \
        kp += 64 * 1024;                                                       \
        vp += 64;                                                              \
    } while (0)
#define WRITEKV()                                                              \
    do {                                                                       \
        _Pragma("unroll") for (int i = 0; i < 4; i++) {                        \
            *(bf16x8*)&KS(krr + i * 16, kc8) = kreg[i];                        \
            *(bf16x8*)&Vs[vrr + i * 32][vc8] = vreg[i];                        \
        }                                                                      \
    } while (0)

    // prologue: tile tbeg staged; tile tbeg+1 loads in flight
    LOADKV();
    WRITEKV();
    if (tbeg + 1 < tend) LOADKV();

    for (int tt = tbeg; tt < tend; tt++) {
        __syncthreads();   // staged K/V tile visible to all waves

        // S^T = K Q^T: A = K-frag, B = Q-frag (identical lane layouts).
        // Result: col(lane&15) = q-row, row(quad*4+r) = key t.
        f32x4 S[2][4];
#pragma unroll
        for (int nt = 0; nt < 4; nt++) {
            f32x4 a0 = fzero, a1 = fzero;
#pragma unroll
            for (int ks = 0; ks < 4; ks++) {
                bf16x8 kf = *(const bf16x8*)&KS(nt * 16 + n, ks * 32 + quad * 8);
                a0 = MFMA16(kf, qf[0][ks], a0);
                a1 = MFMA16(kf, qf[1][ks], a1);
            }
            S[0][nt] = a0;
            S[1][nt] = a1;
        }

        if (tt >= ntot - 2) {   // diagonal band spans the last two tiles
            const int t0 = tt * 64;
#pragma unroll
            for (int mt = 0; mt < 2; mt++) {
                const int lim = 2048 + qr0 + mt * 64 + n;   // q-row = lane index
#pragma unroll
                for (int nt = 0; nt < 4; nt++)
#pragma unroll
                    for (int r = 0; r < 4; r++) {
                        int t = t0 + nt * 16 + quad * 4 + r;
                        if (t > lim) S[mt][nt][r] = -1e30f;
                    }
            }
        }

        // fixed-shift softmax; row-sum is lane-local (lane owns its q-row)
#pragma unroll
        for (int mt = 0; mt < 2; mt++)
#pragma unroll
            for (int nt = 0; nt < 4; nt++)
#pragma unroll
                for (int r = 0; r < 4; r++) {
                    float p = __expf(S[mt][nt][r] - MSTATIC);
                    S[mt][nt][r] = p;
                    l_loc[mt] += p;
                }

        // P -> LDS (per-wave private region; same-wave DS ordering suffices)
#pragma unroll
        for (int mt = 0; mt < 2; mt++)
#pragma unroll
            for (int nt = 0; nt < 4; nt++) {
                bf16x4 pk;
#pragma unroll
                for (int r = 0; r < 4; r++) pk[r] = (__bf16)S[mt][nt][r];
                *(bf16x4*)&PS(w, mt * 16 + n, nt * 16 + quad * 4) = pk;
            }

        bf16x8 pa[2][2];
#pragma unroll
        for (int mt = 0; mt < 2; mt++)
#pragma unroll
            for (int kg = 0; kg < 2; kg++)
                pa[mt][kg] = *(const bf16x8*)&PS(w, mt * 16 + n, kg * 32 + quad * 8);

#pragma unroll
        for (int dt = 0; dt < 8; dt++) {
            bf16x8 vf0 = *(const bf16x8*)&Vs[dt * 16 + n][quad * 8];
            bf16x8 vf1 = *(const bf16x8*)&Vs[dt * 16 + n][32 + quad * 8];
#pragma unroll
            for (int mt = 0; mt < 2; mt++) {
                f32x4 acc = O[mt][dt];
                acc = MFMA16(pa[mt][0], vf0, acc);
                acc = MFMA16(pa[mt][1], vf1, acc);
                O[mt][dt] = acc;
            }
        }

        __syncthreads();   // all Ks/Vs reads done; next tile may be written
        if (tt + 1 < tend) {
            WRITEKV();                    // regs hold tile tt+1
            if (tt + 2 < tend) LOADKV();  // issue loads for tile tt+2
        }
    }
#undef LOADKV
#undef WRITEKV

    // row-sum: reduce across the 4 quads (lane already holds its row's partial)
#pragma unroll
    for (int mt = 0; mt < 2; mt++) {
        float sm = l_loc[mt];
        sm += __shfl_xor(sm, 16);
        sm += __shfl_xor(sm, 32);
        l_loc[mt] = sm;
    }

    __bf16* Op = (s == 0) ? Opart0 : (s == 1 ? Opart1 : Opart2);
    const long tb = (long)(h * 8 + qt) * 128 * 128;
#pragma unroll
    for (int mt = 0; mt < 2; mt++)
#pragma unroll
        for (int dt = 0; dt < 8; dt++)
#pragma unroll
            for (int r = 0; r < 4; r++)
                Op[tb + (long)(mt * 64 + w * 16 + quad * 4 + r) * 128 + dt * 16 + n] =
                    (__bf16)O[mt][dt][r];
    if (quad == 0) {
        const int lb = (s * 256 + h * 8 + qt) * 128 + w * 16;
#pragma unroll
        for (int mt = 0; mt < 2; mt++)
            lsum[lb + mt * 64 + n] = l_loc[mt];
    }
#undef KS
#undef PS
}

// ---------------------------------------------------------------------------
// Additive merge of 3 split-K partials -> normalized bf16 attn-out.
// ---------------------------------------------------------------------------
__global__ __launch_bounds__(256) void flash_merge(const __bf16* __restrict__ O0,
                                                   const __bf16* __restrict__ O1,
                                                   const __bf16* __restrict__ O2,
                                                   const float* __restrict__ lsum,
                                                   __bf16* __restrict__ ob) {
    const int bx = blockIdx.x;         // 512: (h, qt, half64)
    const int h   = bx >> 4;
    const int r6  = bx & 15;
    const int qt  = r6 >> 1;
    const int sub = r6 & 1;
    const int row  = threadIdx.x >> 2;
    const int cseg = (threadIdx.x & 3) * 32;
    const int mrow = sub * 64 + row;

    const int tilei = h * 8 + qt;
    float inv = 1.0f / (lsum[tilei * 128 + mrow] + lsum[(256 + tilei) * 128 + mrow] +
                        lsum[(512 + tilei) * 128 + mrow]);

    const long src = (long)tilei * 128 * 128 + (long)mrow * 128 + cseg;
    __bf16* dst = ob + (long)(qt * 128 + mrow) * 4096 + h * 128 + cseg;
#pragma unroll
    for (int j = 0; j < 4; j++) {
        bf16x8 x0 = *(const bf16x8*)(O0 + src + j * 8);
        bf16x8 x1 = *(const bf16x8*)(O1 + src + j * 8);
        bf16x8 x2 = *(const bf16x8*)(O2 + src + j * 8);
        bf16x8 o;
#pragma unroll
        for (int k = 0; k < 8; k++)
            o[k] = (__bf16)((((float)x0[k] + (float)x1[k]) + (float)x2[k]) * inv);
        *(bf16x8*)(dst + j * 8) = o;
    }
}

// ---------------------------------------------------------------------------
extern "C" void kernel_launch(void* const* d_in, const int* in_sizes, int n_in,
                              void* d_out, int out_size, void* d_ws, size_t ws_size,
                              hipStream_t stream) {
    const float* hidden = (const float*)d_in[0];
    const float* target = (const float*)d_in[1];
    const float* cosb   = (const float*)d_in[2];
    const float* sinb   = (const float*)d_in[3];
    const float* wq = (const float*)d_in[5];
    const float* wk = (const float*)d_in[6];
    const float* wv = (const float*)d_in[7];
    const float* wo = (const float*)d_in[8];
    const float* qw = (const float*)d_in[9];
    const float* kw = (const float*)d_in[10];
    float* out = (float*)d_out;

    // 40 MB workspace overlays (launch order guarantees safety). Layout for
    // 3 flash partials (24 MB):
    //   phase A (conv/kvq):   kbf@0-6  vbf@12-18
    //                         hidb@20-24 tgtb@24-32 wkb@32-36 wvb@36-40
    //   phase A2 (transpose): vtg@6-12
    //   phase B (flash):      reads kbf@0-6, vtg@6-12, qbf(d_out)
    //                         writes Op0@12-20 Op1@20-28 Op2@28-36 lbuf@36-36.4
    //   phase C (merge):      writes attnb@0-8
    //   phase D (wo4/add4):   po1@8-16 po2@16-24 po3@24-32, out=d_out
    char* ws = (char*)d_ws;
    const long MB = 1 << 20;
    __bf16* kbf  = (__bf16*)(ws);             // @0..6
    __bf16* vtg  = (__bf16*)(ws + 6 * MB);    // @6..12
    __bf16* vbf  = (__bf16*)(ws + 12 * MB);   // @12..18
    __bf16* hidb = (__bf16*)(ws + 20 * MB);   // @20..24
    __bf16* tgtb = (__bf16*)(ws + 24 * MB);   // @24..32
    __bf16* wkb  = (__bf16*)(ws + 32 * MB);   // @32..36
    __bf16* wvb  = (__bf16*)(ws + 36 * MB);   // @36..40
    __bf16* Op0  = (__bf16*)(ws + 12 * MB);   // @12..20 (post-transpose)
    __bf16* Op1  = (__bf16*)(ws + 20 * MB);   // @20..28 (post-kvq)
    __bf16* Op2  = (__bf16*)(ws + 28 * MB);   // @28..36 (post-kvq)
    float*  lbuf = (float*)(ws + 36 * MB);    // @36..36.4 (post-kvq)
    __bf16* attnb= (__bf16*)(ws);             // @0..8   (post-flash)
    float*  po1  = (float*)(ws + 8 * MB);     // @8..16  (post-merge)
    float*  po2  = (float*)(ws + 16 * MB);    // @16..24 (post-merge)
    float*  po3  = (float*)(ws + 24 * MB);    // @24..32 (post-merge)
    __bf16* qbf  = (__bf16*)d_out;            // 8MB: q / dead after flash

    dim3 blk(256);

    // activations + k/v weights -> bf16
    conv4_f32_bf16<<<dim3(1024, 4), blk, 0, stream>>>(
        hidden, hidb, (1024 * 2048) / 4, target, tgtb, (2048 * 2048) / 4,
        wk, wkb, (1024 * 2048) / 4, wv, wvb, (1024 * 2048) / 4);

    // all three projections, one launch, 640 blocks all resident
    gemm_kvq<<<640, blk, 0, stream>>>(tgtb, hidb, wkb, wvb, wq, kbf, vbf, qbf);

    // fused RMSNorm + RoPE (q and k)
    rmsnorm_rope2<<<dim3(8192, 2), blk, 0, stream>>>(qbf, qw, kbf, kw, cosb, sinb);

    // V transpose -> [g][d][t]
    transpose_v<<<dim3(48, 2, 8), blk, 0, stream>>>(vbf, vtg);

    // 3-way split-K flash attention (768 blocks) + additive merge
    flash_attn_splitk<<<dim3(256, 3), blk, 0, stream>>>(qbf, kbf, vtg,
                                                        Op0, Op1, Op2, lbuf);
    flash_merge<<<512, blk, 0, stream>>>(Op0, Op1, Op2, lbuf, attnb);

    // output projection: 256x64 fb tiles, split-K=4 (512 blocks) + reduce
    gemm_wo4<<<512, blk, 0, stream>>>(attnb, wo, out, po1, po2, po3);
    add4_wo<<<1024, blk, 0, stream>>>(out, po1, po2, po3, (1024 * 2048) / 4);
}

// Round 9
// 344.379 us; speedup vs baseline: 1.0863x; 1.0523x over previous
//
#include <hip/hip_runtime.h>

#define HIDDEN 2048
#define NQ     1024
#define NCTX   2048
#define NTOT   3072
#define NHEADS 32
#define KVH    8
#define HD     128

typedef __attribute__((ext_vector_type(8))) __bf16 bf16x8;
typedef __attribute__((ext_vector_type(4))) __bf16 bf16x4;
typedef __attribute__((ext_vector_type(4))) float  f32x4;

#define MFMA16(a, b, c) __builtin_amdgcn_mfma_f32_16x16x32_bf16(a, b, c, 0, 0, 0)

// Fixed softmax shift (Cauchy-Schwarz: |q|=1 after folded 1/sqrt(d), |k|=sqrt(128),
// RoPE norm-preserving => s <= 11.4 incl. bf16 rounding).
#define MSTATIC 12.0f

__device__ __forceinline__ void load_lds16(const void* g, void* l) {
    __builtin_amdgcn_global_load_lds(
        (const __attribute__((address_space(1))) unsigned int*)g,
        (__attribute__((address_space(3))) unsigned int*)l, 16, 0, 0);
}

// ---------------------------------------------------------------------------
// 4-way fused fp32 -> bf16 convert (activations + k/v weights)
// ---------------------------------------------------------------------------
__global__ __launch_bounds__(256) void conv4_f32_bf16(const float* __restrict__ s0,
                                                      __bf16* __restrict__ d0, int n0,
                                                      const float* __restrict__ s1,
                                                      __bf16* __restrict__ d1, int n1,
                                                      const float* __restrict__ s2,
                                                      __bf16* __restrict__ d2, int n2,
                                                      const float* __restrict__ s3,
                                                      __bf16* __restrict__ d3, int n3) {
    const float* s; __bf16* d; int n;
    switch (blockIdx.y) {
        case 0:  s = s0; d = d0; n = n0; break;
        case 1:  s = s1; d = d1; n = n1; break;
        case 2:  s = s2; d = d2; n = n2; break;
        default: s = s3; d = d3; n = n3; break;
    }
    int i = blockIdx.x * 256 + threadIdx.x;
    int stride = gridDim.x * 256;
    for (; i < n; i += stride) {
        float4 v = ((const float4*)s)[i];
        bf16x4 o;
        o[0] = (__bf16)v.x; o[1] = (__bf16)v.y;
        o[2] = (__bf16)v.z; o[3] = (__bf16)v.w;
        ((bf16x4*)d)[i] = o;
    }
}

// ---------------------------------------------------------------------------
// 256x64 MFMA GEMM tile bodies (R11-verified: delivery-bound fix, 9.8 B/KFLOP).
// XOR bank-swizzle (R8-verified): linear LDS dest + pre-swizzled global source
// + swizzled read.
//   bb: both operands bf16, pure async global->LDS staging (zero VALU).
//   fb: A bf16 async; B fp32 reg-staged one K-step ahead (T14), cvt->LDS.
// ---------------------------------------------------------------------------
__device__ __forceinline__ void gemm_compute256(const __bf16 (&As)[256][64],
                                                const __bf16 (&Bs)[64][64],
                                                f32x4 (&acc)[4][4],
                                                int wm, int n16, int quad, int rx) {
#pragma unroll
    for (int ks = 0; ks < 2; ks++) {
        bf16x8 af[4], bfr[4];
#pragma unroll
        for (int i = 0; i < 4; i++)
            af[i] = *(const bf16x8*)&As[wm + i * 16 + n16][((ks * 4 + quad) ^ rx) * 8];
#pragma unroll
        for (int j = 0; j < 4; j++)
            bfr[j] = *(const bf16x8*)&Bs[j * 16 + n16][((ks * 4 + quad) ^ rx) * 8];
#pragma unroll
        for (int i = 0; i < 4; i++)
#pragma unroll
            for (int j = 0; j < 4; j++)
                acc[i][j] = MFMA16(af[i], bfr[j], acc[i][j]);
    }
}

template <typename OutT>
__device__ __forceinline__ void gemm_epi256(const f32x4 (&acc)[4][4],
                                            OutT* __restrict__ Cblk, int ldc,
                                            int wm, int n16, int quad) {
#pragma unroll
    for (int i = 0; i < 4; i++)
#pragma unroll
        for (int j = 0; j < 4; j++)
#pragma unroll
            for (int r = 0; r < 4; r++)
                Cblk[(long)(wm + i * 16 + quad * 4 + r) * ldc + j * 16 + n16] =
                    (OutT)acc[i][j][r];
}

template <typename OutT>
__device__ __forceinline__ void gemm25664_bb(__bf16 (&As)[256][64], __bf16 (&Bs)[64][64],
                                             const __bf16* __restrict__ Ablk,
                                             const __bf16* __restrict__ Bblk,
                                             OutT* __restrict__ Cblk,
                                             int K, int lda, int ldb, int ldc) {
    const int tid  = threadIdx.x;
    const int lane = tid & 63;
    const int w    = tid >> 6;
    const int n16  = lane & 15;
    const int quad = lane >> 4;
    const int wm   = w * 64;                      // wave's 64-row m-slab

    f32x4 acc[4][4];
    const f32x4 fzero = {0.f, 0.f, 0.f, 0.f};
#pragma unroll
    for (int i = 0; i < 4; i++)
#pragma unroll
        for (int j = 0; j < 4; j++) acc[i][j] = fzero;

    // Linear LDS dest (gload_lds: wave-uniform base + lane*16); source col
    // pre-XORed so LDS[r][chunk c] holds global chunk c^(r&7).
    const int arow  = w * 64 + (lane >> 3);       // A rows, +8i (i=0..7)
    const int brow  = w * 16 + (lane >> 3);       // B rows, +8i (i=0..1)
    const int sxor  = (lane >> 3) & 7;            // == arow&7 == brow&7
    const int scol  = (lane & 7) * 8;
    const int sgcol = ((lane & 7) ^ sxor) * 8;
    const __bf16* Ap = Ablk + (long)arow * lda + sgcol;
    const __bf16* Bp = Bblk + (long)brow * ldb + sgcol;
    const int rx = n16 & 7;

    for (int k0 = 0; k0 < K; k0 += 64) {
#pragma unroll
        for (int i = 0; i < 8; i++)
            load_lds16(Ap + (long)i * 8 * lda + k0, &As[arow + i * 8][scol]);
#pragma unroll
        for (int i = 0; i < 2; i++)
            load_lds16(Bp + (long)i * 8 * ldb + k0, &Bs[brow + i * 8][scol]);
        __syncthreads();
        gemm_compute256(As, Bs, acc, wm, n16, quad, rx);
        __syncthreads();
    }
    gemm_epi256(acc, Cblk, ldc, wm, n16, quad);
}

template <typename OutT>
__device__ __forceinline__ void gemm25664_fb(__bf16 (&As)[256][64], __bf16 (&Bs)[64][64],
                                             const __bf16* __restrict__ Ablk,
                                             const float* __restrict__ Bblk,
                                             OutT* __restrict__ Cblk,
                                             int K, int lda, int ldb, int ldc) {
    const int tid  = threadIdx.x;
    const int lane = tid & 63;
    const int w    = tid >> 6;
    const int n16  = lane & 15;
    const int quad = lane >> 4;
    const int wm   = w * 64;

    f32x4 acc[4][4];
    const f32x4 fzero = {0.f, 0.f, 0.f, 0.f};
#pragma unroll
    for (int i = 0; i < 4; i++)
#pragma unroll
        for (int j = 0; j < 4; j++) acc[i][j] = fzero;

    const int arow  = w * 64 + (lane >> 3);
    const int sxor  = (lane >> 3) & 7;
    const int scol  = (lane & 7) * 8;
    const int sgcol = ((lane & 7) ^ sxor) * 8;
    const __bf16* Ap = Ablk + (long)arow * lda + sgcol;

    // B: one row per thread (64 rows x 64 fp32 cols = 16 consecutive floats
    // per thread), reg-staged, cvt->bf16, swizzled ds_write (2 chunks).
    const int brr  = tid >> 2;                    // B row 0..63
    const int bc0  = (tid & 3) * 16;              // first of 16 fp32 cols
    const int bch  = (tid & 3) * 2;               // first of 2 bf16x8 chunks
    const int bxor = brr & 7;
    const float* Bptr = Bblk + (long)brr * ldb + bc0;

    const int rx = n16 & 7;
    float4 breg[4];

#define LOAD_B(kk)                                                             \
    _Pragma("unroll") for (int i = 0; i < 4; i++)                              \
        breg[i] = *(const float4*)(Bptr + (kk) + i * 4);

    LOAD_B(0);
    for (int k0 = 0; k0 < K; k0 += 64) {
#pragma unroll
        for (int i = 0; i < 8; i++)
            load_lds16(Ap + (long)i * 8 * lda + k0, &As[arow + i * 8][scol]);
        {
            bf16x8 b0, b1;
#pragma unroll
            for (int j = 0; j < 4; j++) {
                b0[j]     = (__bf16)breg[0][j]; b0[j + 4] = (__bf16)breg[1][j];
                b1[j]     = (__bf16)breg[2][j]; b1[j + 4] = (__bf16)breg[3][j];
            }
            *(bf16x8*)&Bs[brr][((bch + 0) ^ bxor) * 8] = b0;
            *(bf16x8*)&Bs[brr][((bch + 1) ^ bxor) * 8] = b1;
        }
        if (k0 + 64 < K) LOAD_B(k0 + 64);   // in flight across compute below
        __syncthreads();
        gemm_compute256(As, Bs, acc, wm, n16, quad, rx);
        __syncthreads();
    }
#undef LOAD_B
    gemm_epi256(acc, Cblk, ldc, wm, n16, quad);
}

// ---------------------------------------------------------------------------
// Fused k + v + q projections, 640 blocks (all resident at 4/CU LDS cap).
// ---------------------------------------------------------------------------
__global__ __launch_bounds__(256, 4) void gemm_kvq(const __bf16* __restrict__ tgtb,
                                                   const __bf16* __restrict__ hidb,
                                                   const __bf16* __restrict__ wkb,
                                                   const __bf16* __restrict__ wvb,
                                                   const float* __restrict__ wq,
                                                   __bf16* __restrict__ kbf,
                                                   __bf16* __restrict__ vbf,
                                                   __bf16* __restrict__ qbf) {
    __shared__ __bf16 As[256][64];
    __shared__ __bf16 Bs[64][64];
    const int bid = blockIdx.x;
    const int b = (bid & 7) * 80 + (bid >> 3);    // bijective: 640 = 8*80
    if (b < 384) {
        const int z = b >= 192, t = b - z * 192;
        const int m0 = (t >> 4) * 256, n0 = (t & 15) * 64;
        const __bf16* Ap = (m0 < 2048) ? tgtb + (long)m0 * 2048
                                       : hidb + (long)(m0 - 2048) * 2048;
        const __bf16* Bp = (z ? wvb : wkb) + (long)n0 * 2048;
        __bf16* Cp = (z ? vbf : kbf) + (long)m0 * 1024 + n0;
        gemm25664_bb<__bf16>(As, Bs, Ap, Bp, Cp, 2048, 2048, 2048, 1024);
    } else {
        const int t = b - 384;
        const int m0 = (t >> 6) * 256, n0 = (t & 63) * 64;
        gemm25664_fb<__bf16>(As, Bs, hidb + (long)m0 * 2048, wq + (long)n0 * 2048,
                             qbf + (long)m0 * 4096 + n0, 2048, 2048, 2048, 4096);
    }
}

// ---------------------------------------------------------------------------
// Output projection: 256x64 tiles, split-K=4, B = fp32 wo direct (fb path).
// ---------------------------------------------------------------------------
__global__ __launch_bounds__(256, 4) void gemm_wo4(const __bf16* __restrict__ A,
                                                   const float* __restrict__ wo,
                                                   float* __restrict__ out,
                                                   float* __restrict__ p1,
                                                   float* __restrict__ p2,
                                                   float* __restrict__ p3) {
    __shared__ __bf16 As[256][64];
    __shared__ __bf16 Bs[64][64];
    const int bid = blockIdx.x;
    const int b = (bid & 7) * 64 + (bid >> 3);    // bijective: 512 = 8*64
    const int z = b >> 7, t = b & 127;            // 4m x 32n per z
    const int m0 = (t >> 5) * 256, n0 = (t & 31) * 64;
    float* C;
    switch (z) {
        case 0:  C = out; break;
        case 1:  C = p1;  break;
        case 2:  C = p2;  break;
        default: C = p3;  break;
    }
    gemm25664_fb<float>(As, Bs, A + (long)m0 * 4096 + z * 1024,
                        wo + (long)n0 * 4096 + z * 1024,
                        C + (long)m0 * 2048 + n0, 1024, 4096, 4096, 2048);
}

__global__ __launch_bounds__(256) void add4_wo(float* __restrict__ out,
                                               const float* __restrict__ p1,
                                               const float* __restrict__ p2,
                                               const float* __restrict__ p3, int n4) {
    int i = blockIdx.x * 256 + threadIdx.x;
    int stride = gridDim.x * 256;
    for (; i < n4; i += stride) {
        float4 a = ((const float4*)out)[i];
        float4 b = ((const float4*)p1)[i];
        float4 c = ((const float4*)p2)[i];
        float4 d = ((const float4*)p3)[i];
        float4 o;
        o.x = (a.x + b.x) + (c.x + d.x);
        o.y = (a.y + b.y) + (c.y + d.y);
        o.z = (a.z + b.z) + (c.z + d.z);
        o.w = (a.w + b.w) + (c.w + d.w);
        ((float4*)out)[i] = o;
    }
}

// ---------------------------------------------------------------------------
// Fused RMSNorm+RoPE for q (z=0) and k (z=1), in place.
// ---------------------------------------------------------------------------
__global__ __launch_bounds__(256) void rmsnorm_rope2(__bf16* __restrict__ xq,
                                                     const float* __restrict__ wq,
                                                     __bf16* __restrict__ xk,
                                                     const float* __restrict__ wk,
                                                     const float* __restrict__ cosb,
                                                     const float* __restrict__ sinb) {
    const int z = blockIdx.y;
    __bf16*      x = z ? xk : xq;
    const float* w = z ? wk : wq;
    const int nheads     = z ? 8 : 32;
    const int row_stride = z ? 1024 : 4096;
    const int pos_offset = z ? 0 : 2048;
    const float outscale = z ? 1.0f : 0.08838834764831845f;
    const int nitems     = z ? 3072 * 8 : 1024 * 32;

    int item = blockIdx.x * 4 + (threadIdx.x >> 6);
    int lane = threadIdx.x & 63;
    if (item >= nitems) return;
    int row = item / nheads;
    int head = item - row * nheads;
    __bf16* p = x + (long)row * row_stride + head * HD;

    float x1 = (float)p[lane], x2 = (float)p[lane + 64];
    float ss = x1 * x1 + x2 * x2;
#pragma unroll
    for (int o = 32; o >= 1; o >>= 1) ss += __shfl_xor(ss, o);
    float r = rsqrtf(ss * (1.0f / 128.0f) + 1e-6f) * outscale;

    int pos = pos_offset + row;
    float c1 = cosb[pos * HD + lane], c2 = cosb[pos * HD + lane + 64];
    float s1 = sinb[pos * HD + lane], s2 = sinb[pos * HD + lane + 64];
    float y1 = x1 * r * w[lane];
    float y2 = x2 * r * w[lane + 64];
    p[lane]      = (__bf16)(y1 * c1 - y2 * s1);
    p[lane + 64] = (__bf16)(y2 * c2 + y1 * s2);
}

// ---------------------------------------------------------------------------
// V transpose: vbf[t][g*128+d] -> vt[g][d][t]
// ---------------------------------------------------------------------------
__global__ __launch_bounds__(256) void transpose_v(const __bf16* __restrict__ v,
                                                   __bf16* __restrict__ vt) {
    __shared__ __bf16 T[64][68];
    const int tid = threadIdx.x;
    const int t0 = blockIdx.x * 64;
    const int d0 = blockIdx.y * 64;
    const int g  = blockIdx.z;
    const __bf16* src = v + (long)t0 * 1024 + g * 128 + d0;
#pragma unroll
    for (int i = 0; i < 4; i++) {
        int idx = tid + i * 256;
        int r = idx >> 4, c4 = (idx & 15) * 4;
        *(bf16x4*)&T[r][c4] = *(const bf16x4*)(src + (long)r * 1024 + c4);
    }
    __syncthreads();
    __bf16* dst = vt + (long)g * 128 * 3072 + (long)d0 * 3072 + t0;
#pragma unroll
    for (int i = 0; i < 4; i++) {
        int idx = tid + i * 256;
        int r = idx >> 4, c4 = (idx & 15) * 4;
        bf16x4 o;
        o[0] = T[c4 + 0][r]; o[1] = T[c4 + 1][r];
        o[2] = T[c4 + 2][r]; o[3] = T[c4 + 3][r];
        *(bf16x4*)(dst + (long)r * 3072 + c4) = o;
    }
}

// ---------------------------------------------------------------------------
// Split-K flash attention. R16: R15's counters isolated a VGPR cliff — the
// T14 reg-prefetch (kreg/vreg held across compute) pushed allocation to 132
// VGPR, just past the 128 boundary where waves/SIMD halve (4 -> 2), so
// occupancy collapsed (9.2%) and dur regressed vs R12 (103 vs 78.6 us).
// Fix: drop the prefetch; K/V staging is inline global->reg->LDS at the top
// of the loop (R12's binding that compiled to 120 VGPR). KEPT from R13:
//  (1) separate Ps buffer -> 2 barriers/step (R12 had 3);
//  (2) 3-way split-K (768 blocks; LDS 53248 -> 3 blocks/CU at <=128 VGPR).
// S computed TRANSPOSED (S^T = K Q^T); P->LDS packed b64; row-sum lane-local.
// ---------------------------------------------------------------------------
__global__ __launch_bounds__(256) void flash_attn_splitk(const __bf16* __restrict__ qb,
                                                         const __bf16* __restrict__ kb,
                                                         const __bf16* __restrict__ vtg,
                                                         __bf16* __restrict__ Opart0,
                                                         __bf16* __restrict__ Opart1,
                                                         __bf16* __restrict__ Opart2,
                                                         float* __restrict__ lsum) {
    __shared__ __bf16 KsU[64 * 136];   // Ks[t][d] stride 136 (17408 B)
    __shared__ __bf16 Vs[128][72];     // [d][t]              (18432 B)
    __shared__ __bf16 PsU[4 * 32 * 68];// per-wave P tiles    (17408 B)
#define KS(r, c) KsU[(r) * 136 + (c)]
#define PS(w_, m_, t_) PsU[(w_) * 2176 + (m_) * 68 + (t_)]

    const int tid  = threadIdx.x;
    const int lane = tid & 63;
    const int w    = tid >> 6;
    const int n    = lane & 15;
    const int quad = lane >> 4;

    const int bid = blockIdx.x;        // 0..255
    const int s   = blockIdx.y;        // 0..2
    const int g  = bid & 7;
    const int jj = bid >> 3;           // 0..31
    const int h  = g * 4 + (jj & 3);
    const int qt = jj >> 2;            // 0..7, 128-row q tiles

    const int qr0 = qt * 128 + w * 16; // m-tile 0 base; m-tile 1 = +64

    bf16x8 qf[2][4];
#pragma unroll
    for (int mt = 0; mt < 2; mt++) {
        const __bf16* qp = qb + (long)(qr0 + mt * 64 + n) * 4096 + h * 128 + quad * 8;
        qf[mt][0] = *(const bf16x8*)(qp);
        qf[mt][1] = *(const bf16x8*)(qp + 32);
        qf[mt][2] = *(const bf16x8*)(qp + 64);
        qf[mt][3] = *(const bf16x8*)(qp + 96);
    }

    f32x4 O[2][8];
    const f32x4 fzero = {0.f, 0.f, 0.f, 0.f};
#pragma unroll
    for (int mt = 0; mt < 2; mt++)
#pragma unroll
        for (int dt = 0; dt < 8; dt++) O[mt][dt] = fzero;
    float l_loc[2] = {0.f, 0.f};       // lane-local: lane n16 owns q-row qr0+mt*64+n

    const int ntot = 34 + 2 * qt;
    const int tbeg = (s * ntot) / 3;
    const int tend = ((s + 1) * ntot) / 3;

    const int krr = tid >> 4, kc8 = (tid & 15) * 8;
    const int vrr = tid >> 3, vc8 = (tid & 7) * 8;
    const __bf16* kp = kb + g * 128 + (long)(tbeg * 64 + krr) * 1024 + kc8;
    const __bf16* vp = vtg + (long)g * 128 * 3072 + (long)vrr * 3072 + tbeg * 64 + vc8;

    for (int tt = tbeg; tt < tend; tt++) {
        // inline K/V staging (global -> reg -> LDS, compiler-scheduled;
        // no persistent prefetch registers -> stays under the 128-VGPR cliff)
#pragma unroll
        for (int i = 0; i < 4; i++)
            *(bf16x8*)&KS(krr + i * 16, kc8) = *(const bf16x8*)(kp + (long)i * 16 * 1024);
#pragma unroll
        for (int i = 0; i < 4; i++)
            *(bf16x8*)&Vs[vrr + i * 32][vc8] = *(const bf16x8*)(vp + (long)i * 32 * 3072);
        kp += 64 * 1024;
        vp += 64;
        __syncthreads();   // staged K/V tile visible to all waves

        // S^T = K Q^T: A = K-frag, B = Q-frag (identical lane layouts).
        // Result: col(lane&15) = q-row, row(quad*4+r) = key t.
        f32x4 S[2][4];
#pragma unroll
        for (int nt = 0; nt < 4; nt++) {
            f32x4 a0 = fzero, a1 = fzero;
#pragma unroll
            for (int ks = 0; ks < 4; ks++) {
                bf16x8 kf = *(const bf16x8*)&KS(nt * 16 + n, ks * 32 + quad * 8);
                a0 = MFMA16(kf, qf[0][ks], a0);
                a1 = MFMA16(kf, qf[1][ks], a1);
            }
            S[0][nt] = a0;
            S[1][nt] = a1;
        }

        if (tt >= ntot - 2) {   // diagonal band spans the last two tiles
            const int t0 = tt * 64;
#pragma unroll
            for (int mt = 0; mt < 2; mt++) {
                const int lim = 2048 + qr0 + mt * 64 + n;   // q-row = lane index
#pragma unroll
                for (int nt = 0; nt < 4; nt++)
#pragma unroll
                    for (int r = 0; r < 4; r++) {
                        int t = t0 + nt * 16 + quad * 4 + r;
                        if (t > lim) S[mt][nt][r] = -1e30f;
                    }
            }
        }

        // fixed-shift softmax; row-sum is lane-local (lane owns its q-row)
#pragma unroll
        for (int mt = 0; mt < 2; mt++)
#pragma unroll
            for (int nt = 0; nt < 4; nt++)
#pragma unroll
                for (int r = 0; r < 4; r++) {
                    float p = __expf(S[mt][nt][r] - MSTATIC);
                    S[mt][nt][r] = p;
                    l_loc[mt] += p;
                }

        // P -> LDS (per-wave private region; same-wave DS ordering suffices)
#pragma unroll
        for (int mt = 0; mt < 2; mt++)
#pragma unroll
            for (int nt = 0; nt < 4; nt++) {
                bf16x4 pk;
#pragma unroll
                for (int r = 0; r < 4; r++) pk[r] = (__bf16)S[mt][nt][r];
                *(bf16x4*)&PS(w, mt * 16 + n, nt * 16 + quad * 4) = pk;
            }

        bf16x8 pa[2][2];
#pragma unroll
        for (int mt = 0; mt < 2; mt++)
#pragma unroll
            for (int kg = 0; kg < 2; kg++)
                pa[mt][kg] = *(const bf16x8*)&PS(w, mt * 16 + n, kg * 32 + quad * 8);

#pragma unroll
        for (int dt = 0; dt < 8; dt++) {
            bf16x8 vf0 = *(const bf16x8*)&Vs[dt * 16 + n][quad * 8];
            bf16x8 vf1 = *(const bf16x8*)&Vs[dt * 16 + n][32 + quad * 8];
#pragma unroll
            for (int mt = 0; mt < 2; mt++) {
                f32x4 acc = O[mt][dt];
                acc = MFMA16(pa[mt][0], vf0, acc);
                acc = MFMA16(pa[mt][1], vf1, acc);
                O[mt][dt] = acc;
            }
        }

        __syncthreads();   // all Ks/Vs reads done; next tile may be written
    }

    // row-sum: reduce across the 4 quads (lane already holds its row's partial)
#pragma unroll
    for (int mt = 0; mt < 2; mt++) {
        float sm = l_loc[mt];
        sm += __shfl_xor(sm, 16);
        sm += __shfl_xor(sm, 32);
        l_loc[mt] = sm;
    }

    __bf16* Op = (s == 0) ? Opart0 : (s == 1 ? Opart1 : Opart2);
    const long tb = (long)(h * 8 + qt) * 128 * 128;
#pragma unroll
    for (int mt = 0; mt < 2; mt++)
#pragma unroll
        for (int dt = 0; dt < 8; dt++)
#pragma unroll
            for (int r = 0; r < 4; r++)
                Op[tb + (long)(mt * 64 + w * 16 + quad * 4 + r) * 128 + dt * 16 + n] =
                    (__bf16)O[mt][dt][r];
    if (quad == 0) {
        const int lb = (s * 256 + h * 8 + qt) * 128 + w * 16;
#pragma unroll
        for (int mt = 0; mt < 2; mt++)
            lsum[lb + mt * 64 + n] = l_loc[mt];
    }
#undef KS
#undef PS
}

// ---------------------------------------------------------------------------
// Additive merge of 3 split-K partials -> normalized bf16 attn-out.
// ---------------------------------------------------------------------------
__global__ __launch_bounds__(256) void flash_merge(const __bf16* __restrict__ O0,
                                                   const __bf16* __restrict__ O1,
                                                   const __bf16* __restrict__ O2,
                                                   const float* __restrict__ lsum,
                                                   __bf16* __restrict__ ob) {
    const int bx = blockIdx.x;         // 512: (h, qt, half64)
    const int h   = bx >> 4;
    const int r6  = bx & 15;
    const int qt  = r6 >> 1;
    const int sub = r6 & 1;
    const int row  = threadIdx.x >> 2;
    const int cseg = (threadIdx.x & 3) * 32;
    const int mrow = sub * 64 + row;

    const int tilei = h * 8 + qt;
    float inv = 1.0f / (lsum[tilei * 128 + mrow] + lsum[(256 + tilei) * 128 + mrow] +
                        lsum[(512 + tilei) * 128 + mrow]);

    const long src = (long)tilei * 128 * 128 + (long)mrow * 128 + cseg;
    __bf16* dst = ob + (long)(qt * 128 + mrow) * 4096 + h * 128 + cseg;
#pragma unroll
    for (int j = 0; j < 4; j++) {
        bf16x8 x0 = *(const bf16x8*)(O0 + src + j * 8);
        bf16x8 x1 = *(const bf16x8*)(O1 + src + j * 8);
        bf16x8 x2 = *(const bf16x8*)(O2 + src + j * 8);
        bf16x8 o;
#pragma unroll
        for (int k = 0; k < 8; k++)
            o[k] = (__bf16)((((float)x0[k] + (float)x1[k]) + (float)x2[k]) * inv);
        *(bf16x8*)(dst + j * 8) = o;
    }
}

// ---------------------------------------------------------------------------
extern "C" void kernel_launch(void* const* d_in, const int* in_sizes, int n_in,
                              void* d_out, int out_size, void* d_ws, size_t ws_size,
                              hipStream_t stream) {
    const float* hidden = (const float*)d_in[0];
    const float* target = (const float*)d_in[1];
    const float* cosb   = (const float*)d_in[2];
    const float* sinb   = (const float*)d_in[3];
    const float* wq = (const float*)d_in[5];
    const float* wk = (const float*)d_in[6];
    const float* wv = (const float*)d_in[7];
    const float* wo = (const float*)d_in[8];
    const float* qw = (const float*)d_in[9];
    const float* kw = (const float*)d_in[10];
    float* out = (float*)d_out;

    // 40 MB workspace overlays (launch order guarantees safety). Layout for
    // 3 flash partials (24 MB):
    //   phase A (conv/kvq):   kbf@0-6  vbf@12-18
    //                         hidb@20-24 tgtb@24-32 wkb@32-36 wvb@36-40
    //   phase A2 (transpose): vtg@6-12
    //   phase B (flash):      reads kbf@0-6, vtg@6-12, qbf(d_out)
    //                         writes Op0@12-20 Op1@20-28 Op2@28-36 lbuf@36-36.4
    //   phase C (merge):      writes attnb@0-8
    //   phase D (wo4/add4):   po1@8-16 po2@16-24 po3@24-32, out=d_out
    char* ws = (char*)d_ws;
    const long MB = 1 << 20;
    __bf16* kbf  = (__bf16*)(ws);             // @0..6
    __bf16* vtg  = (__bf16*)(ws + 6 * MB);    // @6..12
    __bf16* vbf  = (__bf16*)(ws + 12 * MB);   // @12..18
    __bf16* hidb = (__bf16*)(ws + 20 * MB);   // @20..24
    __bf16* tgtb = (__bf16*)(ws + 24 * MB);   // @24..32
    __bf16* wkb  = (__bf16*)(ws + 32 * MB);   // @32..36
    __bf16* wvb  = (__bf16*)(ws + 36 * MB);   // @36..40
    __bf16* Op0  = (__bf16*)(ws + 12 * MB);   // @12..20 (post-transpose)
    __bf16* Op1  = (__bf16*)(ws + 20 * MB);   // @20..28 (post-kvq)
    __bf16* Op2  = (__bf16*)(ws + 28 * MB);   // @28..36 (post-kvq)
    float*  lbuf = (float*)(ws + 36 * MB);    // @36..36.4 (post-kvq)
    __bf16* attnb= (__bf16*)(ws);             // @0..8   (post-flash)
    float*  po1  = (float*)(ws + 8 * MB);     // @8..16  (post-merge)
    float*  po2  = (float*)(ws + 16 * MB);    // @16..24 (post-merge)
    float*  po3  = (float*)(ws + 24 * MB);    // @24..32 (post-merge)
    __bf16* qbf  = (__bf16*)d_out;            // 8MB: q / dead after flash

    dim3 blk(256);

    // activations + k/v weights -> bf16
    conv4_f32_bf16<<<dim3(1024, 4), blk, 0, stream>>>(
        hidden, hidb, (1024 * 2048) / 4, target, tgtb, (2048 * 2048) / 4,
        wk, wkb, (1024 * 2048) / 4, wv, wvb, (1024 * 2048) / 4);

    // all three projections, one launch, 640 blocks all resident
    gemm_kvq<<<640, blk, 0, stream>>>(tgtb, hidb, wkb, wvb, wq, kbf, vbf, qbf);

    // fused RMSNorm + RoPE (q and k)
    rmsnorm_rope2<<<dim3(8192, 2), blk, 0, stream>>>(qbf, qw, kbf, kw, cosb, sinb);

    // V transpose -> [g][d][t]
    transpose_v<<<dim3(48, 2, 8), blk, 0, stream>>>(vbf, vtg);

    // 3-way split-K flash attention (768 blocks = 3/CU) + additive merge
    flash_attn_splitk<<<dim3(256, 3), blk, 0, stream>>>(qbf, kbf, vtg,
                                                        Op0, Op1, Op2, lbuf);
    flash_merge<<<512, blk, 0, stream>>>(Op0, Op1, Op2, lbuf, attnb);

    // output projection: 256x64 fb tiles, split-K=4 (512 blocks) + reduce
    gemm_wo4<<<512, blk, 0, stream>>>(attnb, wo, out, po1, po2, po3);
    add4_wo<<<1024, blk, 0, stream>>>(out, po1, po2, po3, (1024 * 2048) / 4);
}

// Round 10
// 337.290 us; speedup vs baseline: 1.1091x; 1.0210x over previous
//
#include <hip/hip_runtime.h>

#define HIDDEN 2048
#define NQ     1024
#define NCTX   2048
#define NTOT   3072
#define NHEADS 32
#define KVH    8
#define HD     128

typedef __attribute__((ext_vector_type(8))) __bf16 bf16x8;
typedef __attribute__((ext_vector_type(4))) __bf16 bf16x4;
typedef __attribute__((ext_vector_type(4))) float  f32x4;

#define MFMA16(a, b, c) __builtin_amdgcn_mfma_f32_16x16x32_bf16(a, b, c, 0, 0, 0)

// Fixed softmax shift (Cauchy-Schwarz: |q|=1 after folded 1/sqrt(d), |k|=sqrt(128),
// RoPE norm-preserving => s <= 11.4 incl. bf16 rounding).
#define MSTATIC 12.0f

__device__ __forceinline__ void load_lds16(const void* g, void* l) {
    __builtin_amdgcn_global_load_lds(
        (const __attribute__((address_space(1))) unsigned int*)g,
        (__attribute__((address_space(3))) unsigned int*)l, 16, 0, 0);
}

// ---------------------------------------------------------------------------
// 4-way fused fp32 -> bf16 convert (activations + k/v weights)
// ---------------------------------------------------------------------------
__global__ __launch_bounds__(256) void conv4_f32_bf16(const float* __restrict__ s0,
                                                      __bf16* __restrict__ d0, int n0,
                                                      const float* __restrict__ s1,
                                                      __bf16* __restrict__ d1, int n1,
                                                      const float* __restrict__ s2,
                                                      __bf16* __restrict__ d2, int n2,
                                                      const float* __restrict__ s3,
                                                      __bf16* __restrict__ d3, int n3) {
    const float* s; __bf16* d; int n;
    switch (blockIdx.y) {
        case 0:  s = s0; d = d0; n = n0; break;
        case 1:  s = s1; d = d1; n = n1; break;
        case 2:  s = s2; d = d2; n = n2; break;
        default: s = s3; d = d3; n = n3; break;
    }
    int i = blockIdx.x * 256 + threadIdx.x;
    int stride = gridDim.x * 256;
    for (; i < n; i += stride) {
        float4 v = ((const float4*)s)[i];
        bf16x4 o;
        o[0] = (__bf16)v.x; o[1] = (__bf16)v.y;
        o[2] = (__bf16)v.z; o[3] = (__bf16)v.w;
        ((bf16x4*)d)[i] = o;
    }
}

// ---------------------------------------------------------------------------
// 256x64 MFMA GEMM tile bodies (R11-verified: delivery-bound fix, 9.8 B/KFLOP).
// XOR bank-swizzle (R8-verified): linear LDS dest + pre-swizzled global source
// + swizzled read.
//   bb: both operands bf16, pure async global->LDS staging (zero VALU).
//   fb: A bf16 async; B fp32 reg-staged one K-step ahead (T14), cvt->LDS.
// R17: bb split into core + epilogue so the v-projection can write its output
// TRANSPOSED directly (fuses the old transpose_v kernel away; acc's r-index
// is 4 consecutive t-rows -> natural packed bf16x4 store at vtg[d][t0..t0+3]).
// ---------------------------------------------------------------------------
__device__ __forceinline__ void gemm_compute256(const __bf16 (&As)[256][64],
                                                const __bf16 (&Bs)[64][64],
                                                f32x4 (&acc)[4][4],
                                                int wm, int n16, int quad, int rx) {
#pragma unroll
    for (int ks = 0; ks < 2; ks++) {
        bf16x8 af[4], bfr[4];
#pragma unroll
        for (int i = 0; i < 4; i++)
            af[i] = *(const bf16x8*)&As[wm + i * 16 + n16][((ks * 4 + quad) ^ rx) * 8];
#pragma unroll
        for (int j = 0; j < 4; j++)
            bfr[j] = *(const bf16x8*)&Bs[j * 16 + n16][((ks * 4 + quad) ^ rx) * 8];
#pragma unroll
        for (int i = 0; i < 4; i++)
#pragma unroll
            for (int j = 0; j < 4; j++)
                acc[i][j] = MFMA16(af[i], bfr[j], acc[i][j]);
    }
}

template <typename OutT>
__device__ __forceinline__ void gemm_epi256(const f32x4 (&acc)[4][4],
                                            OutT* __restrict__ Cblk, int ldc,
                                            int wm, int n16, int quad) {
#pragma unroll
    for (int i = 0; i < 4; i++)
#pragma unroll
        for (int j = 0; j < 4; j++)
#pragma unroll
            for (int r = 0; r < 4; r++)
                Cblk[(long)(wm + i * 16 + quad * 4 + r) * ldc + j * 16 + n16] =
                    (OutT)acc[i][j][r];
}

// Transposed epilogue for v: base = vtg + g*128*3072 + (n0&127)*3072;
// element (t = m0+wm+i*16+quad*4+r, d = j*16+n16) -> base[d*3072 + t].
__device__ __forceinline__ void gemm_epi256_vT(const f32x4 (&acc)[4][4],
                                               __bf16* __restrict__ base,
                                               int m0, int wm, int n16, int quad) {
#pragma unroll
    for (int i = 0; i < 4; i++)
#pragma unroll
        for (int j = 0; j < 4; j++) {
            bf16x4 o;
#pragma unroll
            for (int r = 0; r < 4; r++) o[r] = (__bf16)acc[i][j][r];
            *(bf16x4*)(base + (long)(j * 16 + n16) * 3072 +
                       (m0 + wm + i * 16 + quad * 4)) = o;
        }
}

__device__ __forceinline__ void gemm25664_bb_core(__bf16 (&As)[256][64],
                                                  __bf16 (&Bs)[64][64],
                                                  const __bf16* __restrict__ Ablk,
                                                  const __bf16* __restrict__ Bblk,
                                                  f32x4 (&acc)[4][4],
                                                  int K, int lda, int ldb) {
    const int tid  = threadIdx.x;
    const int lane = tid & 63;
    const int w    = tid >> 6;
    const int n16  = lane & 15;
    const int quad = lane >> 4;
    const int wm   = w * 64;

    // Linear LDS dest (gload_lds: wave-uniform base + lane*16); source col
    // pre-XORed so LDS[r][chunk c] holds global chunk c^(r&7).
    const int arow  = w * 64 + (lane >> 3);       // A rows, +8i (i=0..7)
    const int brow  = w * 16 + (lane >> 3);       // B rows, +8i (i=0..1)
    const int sxor  = (lane >> 3) & 7;            // == arow&7 == brow&7
    const int scol  = (lane & 7) * 8;
    const int sgcol = ((lane & 7) ^ sxor) * 8;
    const __bf16* Ap = Ablk + (long)arow * lda + sgcol;
    const __bf16* Bp = Bblk + (long)brow * ldb + sgcol;
    const int rx = n16 & 7;

    for (int k0 = 0; k0 < K; k0 += 64) {
#pragma unroll
        for (int i = 0; i < 8; i++)
            load_lds16(Ap + (long)i * 8 * lda + k0, &As[arow + i * 8][scol]);
#pragma unroll
        for (int i = 0; i < 2; i++)
            load_lds16(Bp + (long)i * 8 * ldb + k0, &Bs[brow + i * 8][scol]);
        __syncthreads();
        gemm_compute256(As, Bs, acc, wm, n16, quad, rx);
        __syncthreads();
    }
}

template <typename OutT>
__device__ __forceinline__ void gemm25664_fb(__bf16 (&As)[256][64], __bf16 (&Bs)[64][64],
                                             const __bf16* __restrict__ Ablk,
                                             const float* __restrict__ Bblk,
                                             OutT* __restrict__ Cblk,
                                             int K, int lda, int ldb, int ldc) {
    const int tid  = threadIdx.x;
    const int lane = tid & 63;
    const int w    = tid >> 6;
    const int n16  = lane & 15;
    const int quad = lane >> 4;
    const int wm   = w * 64;

    f32x4 acc[4][4];
    const f32x4 fzero = {0.f, 0.f, 0.f, 0.f};
#pragma unroll
    for (int i = 0; i < 4; i++)
#pragma unroll
        for (int j = 0; j < 4; j++) acc[i][j] = fzero;

    const int arow  = w * 64 + (lane >> 3);
    const int sxor  = (lane >> 3) & 7;
    const int scol  = (lane & 7) * 8;
    const int sgcol = ((lane & 7) ^ sxor) * 8;
    const __bf16* Ap = Ablk + (long)arow * lda + sgcol;

    // B: one row per thread (64 rows x 64 fp32 cols = 16 consecutive floats
    // per thread), reg-staged, cvt->bf16, swizzled ds_write (2 chunks).
    const int brr  = tid >> 2;                    // B row 0..63
    const int bc0  = (tid & 3) * 16;              // first of 16 fp32 cols
    const int bch  = (tid & 3) * 2;               // first of 2 bf16x8 chunks
    const int bxor = brr & 7;
    const float* Bptr = Bblk + (long)brr * ldb + bc0;

    const int rx = n16 & 7;
    float4 breg[4];

#define LOAD_B(kk)                                                             \
    _Pragma("unroll") for (int i = 0; i < 4; i++)                              \
        breg[i] = *(const float4*)(Bptr + (kk) + i * 4);

    LOAD_B(0);
    for (int k0 = 0; k0 < K; k0 += 64) {
#pragma unroll
        for (int i = 0; i < 8; i++)
            load_lds16(Ap + (long)i * 8 * lda + k0, &As[arow + i * 8][scol]);
        {
            bf16x8 b0, b1;
#pragma unroll
            for (int j = 0; j < 4; j++) {
                b0[j]     = (__bf16)breg[0][j]; b0[j + 4] = (__bf16)breg[1][j];
                b1[j]     = (__bf16)breg[2][j]; b1[j + 4] = (__bf16)breg[3][j];
            }
            *(bf16x8*)&Bs[brr][((bch + 0) ^ bxor) * 8] = b0;
            *(bf16x8*)&Bs[brr][((bch + 1) ^ bxor) * 8] = b1;
        }
        if (k0 + 64 < K) LOAD_B(k0 + 64);   // in flight across compute below
        __syncthreads();
        gemm_compute256(As, Bs, acc, wm, n16, quad, rx);
        __syncthreads();
    }
#undef LOAD_B
    gemm_epi256(acc, Cblk, ldc, wm, n16, quad);
}

// ---------------------------------------------------------------------------
// Fused k + v + q projections, 640 blocks (all resident at 4/CU LDS cap).
// v output is written TRANSPOSED straight to vtg[g][d][t] (transpose_v fused).
// ---------------------------------------------------------------------------
__global__ __launch_bounds__(256, 4) void gemm_kvq(const __bf16* __restrict__ tgtb,
                                                   const __bf16* __restrict__ hidb,
                                                   const __bf16* __restrict__ wkb,
                                                   const __bf16* __restrict__ wvb,
                                                   const float* __restrict__ wq,
                                                   __bf16* __restrict__ kbf,
                                                   __bf16* __restrict__ vtg,
                                                   __bf16* __restrict__ qbf) {
    __shared__ __bf16 As[256][64];
    __shared__ __bf16 Bs[64][64];
    const int tid  = threadIdx.x;
    const int lane = tid & 63;
    const int w    = tid >> 6;
    const int n16  = lane & 15;
    const int quad = lane >> 4;
    const int wm   = w * 64;

    const int bid = blockIdx.x;
    const int b = (bid & 7) * 80 + (bid >> 3);    // bijective: 640 = 8*80
    if (b < 384) {
        const int z = b >= 192, t = b - z * 192;
        const int m0 = (t >> 4) * 256, n0 = (t & 15) * 64;
        const __bf16* Ap = (m0 < 2048) ? tgtb + (long)m0 * 2048
                                       : hidb + (long)(m0 - 2048) * 2048;
        const __bf16* Bp = (z ? wvb : wkb) + (long)n0 * 2048;
        f32x4 acc[4][4];
        const f32x4 fzero = {0.f, 0.f, 0.f, 0.f};
#pragma unroll
        for (int i = 0; i < 4; i++)
#pragma unroll
            for (int j = 0; j < 4; j++) acc[i][j] = fzero;
        gemm25664_bb_core(As, Bs, Ap, Bp, acc, 2048, 2048, 2048);
        if (z) {
            // transposed v store: vtg + g*128*3072 + d_local_base*3072
            __bf16* base = vtg + (long)(n0 >> 7) * 128 * 3072 + (long)(n0 & 127) * 3072;
            gemm_epi256_vT(acc, base, m0, wm, n16, quad);
        } else {
            gemm_epi256<__bf16>(acc, kbf + (long)m0 * 1024 + n0, 1024, wm, n16, quad);
        }
    } else {
        const int t = b - 384;
        const int m0 = (t >> 6) * 256, n0 = (t & 63) * 64;
        gemm25664_fb<__bf16>(As, Bs, hidb + (long)m0 * 2048, wq + (long)n0 * 2048,
                             qbf + (long)m0 * 4096 + n0, 2048, 2048, 2048, 4096);
    }
}

// ---------------------------------------------------------------------------
// Output projection: 256x64 tiles, split-K=4, B = fp32 wo direct (fb path).
// ---------------------------------------------------------------------------
__global__ __launch_bounds__(256, 4) void gemm_wo4(const __bf16* __restrict__ A,
                                                   const float* __restrict__ wo,
                                                   float* __restrict__ out,
                                                   float* __restrict__ p1,
                                                   float* __restrict__ p2,
                                                   float* __restrict__ p3) {
    __shared__ __bf16 As[256][64];
    __shared__ __bf16 Bs[64][64];
    const int bid = blockIdx.x;
    const int b = (bid & 7) * 64 + (bid >> 3);    // bijective: 512 = 8*64
    const int z = b >> 7, t = b & 127;            // 4m x 32n per z
    const int m0 = (t >> 5) * 256, n0 = (t & 31) * 64;
    float* C;
    switch (z) {
        case 0:  C = out; break;
        case 1:  C = p1;  break;
        case 2:  C = p2;  break;
        default: C = p3;  break;
    }
    gemm25664_fb<float>(As, Bs, A + (long)m0 * 4096 + z * 1024,
                        wo + (long)n0 * 4096 + z * 1024,
                        C + (long)m0 * 2048 + n0, 1024, 4096, 4096, 2048);
}

__global__ __launch_bounds__(256) void add4_wo(float* __restrict__ out,
                                               const float* __restrict__ p1,
                                               const float* __restrict__ p2,
                                               const float* __restrict__ p3, int n4) {
    int i = blockIdx.x * 256 + threadIdx.x;
    int stride = gridDim.x * 256;
    for (; i < n4; i += stride) {
        float4 a = ((const float4*)out)[i];
        float4 b = ((const float4*)p1)[i];
        float4 c = ((const float4*)p2)[i];
        float4 d = ((const float4*)p3)[i];
        float4 o;
        o.x = (a.x + b.x) + (c.x + d.x);
        o.y = (a.y + b.y) + (c.y + d.y);
        o.z = (a.z + b.z) + (c.z + d.z);
        o.w = (a.w + b.w) + (c.w + d.w);
        ((float4*)out)[i] = o;
    }
}

// ---------------------------------------------------------------------------
// Fused RMSNorm+RoPE for q (z=0) and k (z=1), in place.
// ---------------------------------------------------------------------------
__global__ __launch_bounds__(256) void rmsnorm_rope2(__bf16* __restrict__ xq,
                                                     const float* __restrict__ wq,
                                                     __bf16* __restrict__ xk,
                                                     const float* __restrict__ wk,
                                                     const float* __restrict__ cosb,
                                                     const float* __restrict__ sinb) {
    const int z = blockIdx.y;
    __bf16*      x = z ? xk : xq;
    const float* w = z ? wk : wq;
    const int nheads     = z ? 8 : 32;
    const int row_stride = z ? 1024 : 4096;
    const int pos_offset = z ? 0 : 2048;
    const float outscale = z ? 1.0f : 0.08838834764831845f;
    const int nitems     = z ? 3072 * 8 : 1024 * 32;

    int item = blockIdx.x * 4 + (threadIdx.x >> 6);
    int lane = threadIdx.x & 63;
    if (item >= nitems) return;
    int row = item / nheads;
    int head = item - row * nheads;
    __bf16* p = x + (long)row * row_stride + head * HD;

    float x1 = (float)p[lane], x2 = (float)p[lane + 64];
    float ss = x1 * x1 + x2 * x2;
#pragma unroll
    for (int o = 32; o >= 1; o >>= 1) ss += __shfl_xor(ss, o);
    float r = rsqrtf(ss * (1.0f / 128.0f) + 1e-6f) * outscale;

    int pos = pos_offset + row;
    float c1 = cosb[pos * HD + lane], c2 = cosb[pos * HD + lane + 64];
    float s1 = sinb[pos * HD + lane], s2 = sinb[pos * HD + lane + 64];
    float y1 = x1 * r * w[lane];
    float y2 = x2 * r * w[lane + 64];
    p[lane]      = (__bf16)(y1 * c1 - y2 * s1);
    p[lane + 64] = (__bf16)(y2 * c2 + y1 * s2);
}

// ---------------------------------------------------------------------------
// Split-K flash attention. R17: the clean combination isolated by R12/R16:
//  - 2-way split-K (R16's 3-way cost +50% partial traffic + Q re-reads and
//    ran 82.6 vs R12's 78.6);
//  - separate Ps buffer -> 2 barriers/step (R13/R16-verified innocent);
//  - inline K/V staging, no reg prefetch (R16-verified: 120 VGPR, under the
//    128 cliff; the R15 prefetch cost occupancy 4->2 waves/SIMD).
// S computed TRANSPOSED (S^T = K Q^T); P->LDS packed b64; row-sum lane-local.
// ---------------------------------------------------------------------------
__global__ __launch_bounds__(256) void flash_attn_splitk(const __bf16* __restrict__ qb,
                                                         const __bf16* __restrict__ kb,
                                                         const __bf16* __restrict__ vtg,
                                                         __bf16* __restrict__ Opart0,
                                                         __bf16* __restrict__ Opart1,
                                                         float* __restrict__ lsum) {
    __shared__ __bf16 KsU[64 * 136];   // Ks[t][d] stride 136 (17408 B)
    __shared__ __bf16 Vs[128][72];     // [d][t]              (18432 B)
    __shared__ __bf16 PsU[4 * 32 * 68];// per-wave P tiles    (17408 B)
#define KS(r, c) KsU[(r) * 136 + (c)]
#define PS(w_, m_, t_) PsU[(w_) * 2176 + (m_) * 68 + (t_)]

    const int tid  = threadIdx.x;
    const int lane = tid & 63;
    const int w    = tid >> 6;
    const int n    = lane & 15;
    const int quad = lane >> 4;

    const int bid = blockIdx.x;        // 0..255
    const int s   = blockIdx.y;        // 0..1
    const int g  = bid & 7;
    const int jj = bid >> 3;           // 0..31
    const int h  = g * 4 + (jj & 3);
    const int qt = jj >> 2;            // 0..7, 128-row q tiles

    const int qr0 = qt * 128 + w * 16; // m-tile 0 base; m-tile 1 = +64

    bf16x8 qf[2][4];
#pragma unroll
    for (int mt = 0; mt < 2; mt++) {
        const __bf16* qp = qb + (long)(qr0 + mt * 64 + n) * 4096 + h * 128 + quad * 8;
        qf[mt][0] = *(const bf16x8*)(qp);
        qf[mt][1] = *(const bf16x8*)(qp + 32);
        qf[mt][2] = *(const bf16x8*)(qp + 64);
        qf[mt][3] = *(const bf16x8*)(qp + 96);
    }

    f32x4 O[2][8];
    const f32x4 fzero = {0.f, 0.f, 0.f, 0.f};
#pragma unroll
    for (int mt = 0; mt < 2; mt++)
#pragma unroll
        for (int dt = 0; dt < 8; dt++) O[mt][dt] = fzero;
    float l_loc[2] = {0.f, 0.f};       // lane-local: lane n16 owns q-row qr0+mt*64+n

    const int ntot = 34 + 2 * qt;      // even
    const int half = ntot >> 1;
    const int tbeg = s ? half : 0;
    const int tend = s ? ntot : half;

    const int krr = tid >> 4, kc8 = (tid & 15) * 8;
    const int vrr = tid >> 3, vc8 = (tid & 7) * 8;
    const __bf16* kp = kb + g * 128 + (long)(tbeg * 64 + krr) * 1024 + kc8;
    const __bf16* vp = vtg + (long)g * 128 * 3072 + (long)vrr * 3072 + tbeg * 64 + vc8;

    for (int tt = tbeg; tt < tend; tt++) {
        // inline K/V staging (global -> reg -> LDS, compiler-scheduled;
        // no persistent prefetch registers -> stays under the 128-VGPR cliff)
#pragma unroll
        for (int i = 0; i < 4; i++)
            *(bf16x8*)&KS(krr + i * 16, kc8) = *(const bf16x8*)(kp + (long)i * 16 * 1024);
#pragma unroll
        for (int i = 0; i < 4; i++)
            *(bf16x8*)&Vs[vrr + i * 32][vc8] = *(const bf16x8*)(vp + (long)i * 32 * 3072);
        kp += 64 * 1024;
        vp += 64;
        __syncthreads();   // staged K/V tile visible to all waves

        // S^T = K Q^T: A = K-frag, B = Q-frag (identical lane layouts).
        // Result: col(lane&15) = q-row, row(quad*4+r) = key t.
        f32x4 S[2][4];
#pragma unroll
        for (int nt = 0; nt < 4; nt++) {
            f32x4 a0 = fzero, a1 = fzero;
#pragma unroll
            for (int ks = 0; ks < 4; ks++) {
                bf16x8 kf = *(const bf16x8*)&KS(nt * 16 + n, ks * 32 + quad * 8);
                a0 = MFMA16(kf, qf[0][ks], a0);
                a1 = MFMA16(kf, qf[1][ks], a1);
            }
            S[0][nt] = a0;
            S[1][nt] = a1;
        }

        if (tt >= ntot - 2) {   // diagonal band spans the last two tiles
            const int t0 = tt * 64;
#pragma unroll
            for (int mt = 0; mt < 2; mt++) {
                const int lim = 2048 + qr0 + mt * 64 + n;   // q-row = lane index
#pragma unroll
                for (int nt = 0; nt < 4; nt++)
#pragma unroll
                    for (int r = 0; r < 4; r++) {
                        int t = t0 + nt * 16 + quad * 4 + r;
                        if (t > lim) S[mt][nt][r] = -1e30f;
                    }
            }
        }

        // fixed-shift softmax; row-sum is lane-local (lane owns its q-row)
#pragma unroll
        for (int mt = 0; mt < 2; mt++)
#pragma unroll
            for (int nt = 0; nt < 4; nt++)
#pragma unroll
                for (int r = 0; r < 4; r++) {
                    float p = __expf(S[mt][nt][r] - MSTATIC);
                    S[mt][nt][r] = p;
                    l_loc[mt] += p;
                }

        // P -> LDS (per-wave private region; same-wave DS ordering suffices)
#pragma unroll
        for (int mt = 0; mt < 2; mt++)
#pragma unroll
            for (int nt = 0; nt < 4; nt++) {
                bf16x4 pk;
#pragma unroll
                for (int r = 0; r < 4; r++) pk[r] = (__bf16)S[mt][nt][r];
                *(bf16x4*)&PS(w, mt * 16 + n, nt * 16 + quad * 4) = pk;
            }

        bf16x8 pa[2][2];
#pragma unroll
        for (int mt = 0; mt < 2; mt++)
#pragma unroll
            for (int kg = 0; kg < 2; kg++)
                pa[mt][kg] = *(const bf16x8*)&PS(w, mt * 16 + n, kg * 32 + quad * 8);

#pragma unroll
        for (int dt = 0; dt < 8; dt++) {
            bf16x8 vf0 = *(const bf16x8*)&Vs[dt * 16 + n][quad * 8];
            bf16x8 vf1 = *(const bf16x8*)&Vs[dt * 16 + n][32 + quad * 8];
#pragma unroll
            for (int mt = 0; mt < 2; mt++) {
                f32x4 acc = O[mt][dt];
                acc = MFMA16(pa[mt][0], vf0, acc);
                acc = MFMA16(pa[mt][1], vf1, acc);
                O[mt][dt] = acc;
            }
        }

        __syncthreads();   // all Ks/Vs reads done; next tile may be written
    }

    // row-sum: reduce across the 4 quads (lane already holds its row's partial)
#pragma unroll
    for (int mt = 0; mt < 2; mt++) {
        float sm = l_loc[mt];
        sm += __shfl_xor(sm, 16);
        sm += __shfl_xor(sm, 32);
        l_loc[mt] = sm;
    }

    __bf16* Op = s ? Opart1 : Opart0;
    const long tb = (long)(h * 8 + qt) * 128 * 128;
#pragma unroll
    for (int mt = 0; mt < 2; mt++)
#pragma unroll
        for (int dt = 0; dt < 8; dt++)
#pragma unroll
            for (int r = 0; r < 4; r++)
                Op[tb + (long)(mt * 64 + w * 16 + quad * 4 + r) * 128 + dt * 16 + n] =
                    (__bf16)O[mt][dt][r];
    if (quad == 0) {
        const int lb = (s * 256 + h * 8 + qt) * 128 + w * 16;
#pragma unroll
        for (int mt = 0; mt < 2; mt++)
            lsum[lb + mt * 64 + n] = l_loc[mt];
    }
#undef KS
#undef PS
}

// ---------------------------------------------------------------------------
// Additive merge of 2 split-K partials -> normalized bf16 attn-out.
// ---------------------------------------------------------------------------
__global__ __launch_bounds__(256) void flash_merge(const __bf16* __restrict__ O0,
                                                   const __bf16* __restrict__ O1,
                                                   const float* __restrict__ lsum,
                                                   __bf16* __restrict__ ob) {
    const int bx = blockIdx.x;         // 512: (h, qt, half64)
    const int h   = bx >> 4;
    const int r6  = bx & 15;
    const int qt  = r6 >> 1;
    const int sub = r6 & 1;
    const int row  = threadIdx.x >> 2;
    const int cseg = (threadIdx.x & 3) * 32;
    const int mrow = sub * 64 + row;

    const int tilei = h * 8 + qt;
    float inv = 1.0f / (lsum[tilei * 128 + mrow] + lsum[(256 + tilei) * 128 + mrow]);

    const long src = (long)tilei * 128 * 128 + (long)mrow * 128 + cseg;
    __bf16* dst = ob + (long)(qt * 128 + mrow) * 4096 + h * 128 + cseg;
#pragma unroll
    for (int j = 0; j < 4; j++) {
        bf16x8 x0 = *(const bf16x8*)(O0 + src + j * 8);
        bf16x8 x1 = *(const bf16x8*)(O1 + src + j * 8);
        bf16x8 o;
#pragma unroll
        for (int k = 0; k < 8; k++)
            o[k] = (__bf16)(((float)x0[k] + (float)x1[k]) * inv);
        *(bf16x8*)(dst + j * 8) = o;
    }
}

// ---------------------------------------------------------------------------
extern "C" void kernel_launch(void* const* d_in, const int* in_sizes, int n_in,
                              void* d_out, int out_size, void* d_ws, size_t ws_size,
                              hipStream_t stream) {
    const float* hidden = (const float*)d_in[0];
    const float* target = (const float*)d_in[1];
    const float* cosb   = (const float*)d_in[2];
    const float* sinb   = (const float*)d_in[3];
    const float* wq = (const float*)d_in[5];
    const float* wk = (const float*)d_in[6];
    const float* wv = (const float*)d_in[7];
    const float* wo = (const float*)d_in[8];
    const float* qw = (const float*)d_in[9];
    const float* kw = (const float*)d_in[10];
    float* out = (float*)d_out;

    // 40 MB workspace overlays (launch order guarantees safety):
    //   phase A (conv/kvq):   kbf@0-6, vtg@6-12 (v written transposed by kvq)
    //                         hidb@20-24 tgtb@24-32 wkb@32-36 wvb@36-40
    //   phase B (flash):      reads kbf@0-6, vtg@6-12, qbf(d_out)
    //                         writes Op0@12-20 Op1@20-28 lbuf@36-36.3
    //   phase C (merge):      writes attnb@0-8
    //   phase D (wo4/add4):   po1@8-16 po2@16-24 po3@28-36, out=d_out
    char* ws = (char*)d_ws;
    const long MB = 1 << 20;
    __bf16* kbf  = (__bf16*)(ws);             // @0..6
    __bf16* vtg  = (__bf16*)(ws + 6 * MB);    // @6..12  (written by kvq)
    __bf16* hidb = (__bf16*)(ws + 20 * MB);   // @20..24
    __bf16* tgtb = (__bf16*)(ws + 24 * MB);   // @24..32
    __bf16* wkb  = (__bf16*)(ws + 32 * MB);   // @32..36
    __bf16* wvb  = (__bf16*)(ws + 36 * MB);   // @36..40
    __bf16* Op0  = (__bf16*)(ws + 12 * MB);   // @12..20 (post-kvq)
    __bf16* Op1  = (__bf16*)(ws + 20 * MB);   // @20..28 (post-kvq)
    float*  lbuf = (float*)(ws + 36 * MB);    // @36..36.3 (post-kvq)
    __bf16* attnb= (__bf16*)(ws);             // @0..8   (post-flash)
    float*  po1  = (float*)(ws + 8 * MB);     // @8..16  (post-merge)
    float*  po2  = (float*)(ws + 16 * MB);    // @16..24 (post-merge)
    float*  po3  = (float*)(ws + 28 * MB);    // @28..36 (post-merge)
    __bf16* qbf  = (__bf16*)d_out;            // 8MB: q / dead after flash

    dim3 blk(256);

    // activations + k/v weights -> bf16
    conv4_f32_bf16<<<dim3(1024, 4), blk, 0, stream>>>(
        hidden, hidb, (1024 * 2048) / 4, target, tgtb, (2048 * 2048) / 4,
        wk, wkb, (1024 * 2048) / 4, wv, wvb, (1024 * 2048) / 4);

    // all three projections, one launch; v stored transposed (no transpose_v)
    gemm_kvq<<<640, blk, 0, stream>>>(tgtb, hidb, wkb, wvb, wq, kbf, vtg, qbf);

    // fused RMSNorm + RoPE (q and k)
    rmsnorm_rope2<<<dim3(8192, 2), blk, 0, stream>>>(qbf, qw, kbf, kw, cosb, sinb);

    // 2-way split-K flash attention (512 blocks) + additive merge
    flash_attn_splitk<<<dim3(256, 2), blk, 0, stream>>>(qbf, kbf, vtg,
                                                        Op0, Op1, lbuf);
    flash_merge<<<512, blk, 0, stream>>>(Op0, Op1, lbuf, attnb);

    // output projection: 256x64 fb tiles, split-K=4 (512 blocks) + reduce
    gemm_wo4<<<512, blk, 0, stream>>>(attnb, wo, out, po1, po2, po3);
    add4_wo<<<1024, blk, 0, stream>>>(out, po1, po2, po3, (1024 * 2048) / 4);
}

// Round 12
// 331.197 us; speedup vs baseline: 1.1295x; 1.0184x over previous
//
#include <hip/hip_runtime.h>

#define HIDDEN 2048
#define NQ     1024
#define NCTX   2048
#define NTOT   3072
#define NHEADS 32
#define KVH    8
#define HD     128

typedef __attribute__((ext_vector_type(8))) __bf16 bf16x8;
typedef __attribute__((ext_vector_type(4))) __bf16 bf16x4;
typedef __attribute__((ext_vector_type(4))) float  f32x4;

#define MFMA16(a, b, c) __builtin_amdgcn_mfma_f32_16x16x32_bf16(a, b, c, 0, 0, 0)

// Fixed softmax shift (Cauchy-Schwarz: |q|=1 after folded 1/sqrt(d), |k|=sqrt(128),
// RoPE norm-preserving => s <= 11.4 incl. bf16 rounding).
#define MSTATIC 12.0f

__device__ __forceinline__ void load_lds16(const void* g, void* l) {
    __builtin_amdgcn_global_load_lds(
        (const __attribute__((address_space(1))) unsigned int*)g,
        (__attribute__((address_space(3))) unsigned int*)l, 16, 0, 0);
}

// ---------------------------------------------------------------------------
// 4-way fused fp32 -> bf16 convert (activations + k/v weights).
// R19 note: R18 tried a 5th stream (full bf16 wq = 16 MB) — it does NOT fit
// the 40 MB phase-A live set (48 MB needed) and corrupted hidb/tgtb. q stays fb.
// ---------------------------------------------------------------------------
__global__ __launch_bounds__(256) void conv4_f32_bf16(const float* __restrict__ s0,
                                                      __bf16* __restrict__ d0, int n0,
                                                      const float* __restrict__ s1,
                                                      __bf16* __restrict__ d1, int n1,
                                                      const float* __restrict__ s2,
                                                      __bf16* __restrict__ d2, int n2,
                                                      const float* __restrict__ s3,
                                                      __bf16* __restrict__ d3, int n3) {
    const float* s; __bf16* d; int n;
    switch (blockIdx.y) {
        case 0:  s = s0; d = d0; n = n0; break;
        case 1:  s = s1; d = d1; n = n1; break;
        case 2:  s = s2; d = d2; n = n2; break;
        default: s = s3; d = d3; n = n3; break;
    }
    int i = blockIdx.x * 256 + threadIdx.x;
    int stride = gridDim.x * 256;
    for (; i < n; i += stride) {
        float4 v = ((const float4*)s)[i];
        bf16x4 o;
        o[0] = (__bf16)v.x; o[1] = (__bf16)v.y;
        o[2] = (__bf16)v.z; o[3] = (__bf16)v.w;
        ((bf16x4*)d)[i] = o;
    }
}

// ---------------------------------------------------------------------------
// 256x64 MFMA GEMM tile bodies (R11-verified: delivery-bound fix, 9.8 B/KFLOP).
// XOR bank-swizzle (R8-verified: conflicts -> 0): linear LDS dest (gload_lds
// requirement) + pre-swizzled global source + swizzled read.
//   bb: both operands bf16, pure async global->LDS staging (zero VALU).
//   fb: A bf16 async; B fp32 reg-staged one K-step ahead (T14), cvt->LDS.
// ---------------------------------------------------------------------------
__device__ __forceinline__ void gemm_compute256(const __bf16 (&As)[256][64],
                                                const __bf16 (&Bs)[64][64],
                                                f32x4 (&acc)[4][4],
                                                int wm, int n16, int quad, int rx) {
#pragma unroll
    for (int ks = 0; ks < 2; ks++) {
        bf16x8 af[4], bfr[4];
#pragma unroll
        for (int i = 0; i < 4; i++)
            af[i] = *(const bf16x8*)&As[wm + i * 16 + n16][((ks * 4 + quad) ^ rx) * 8];
#pragma unroll
        for (int j = 0; j < 4; j++)
            bfr[j] = *(const bf16x8*)&Bs[j * 16 + n16][((ks * 4 + quad) ^ rx) * 8];
#pragma unroll
        for (int i = 0; i < 4; i++)
#pragma unroll
            for (int j = 0; j < 4; j++)
                acc[i][j] = MFMA16(af[i], bfr[j], acc[i][j]);
    }
}

template <typename OutT>
__device__ __forceinline__ void gemm_epi256(const f32x4 (&acc)[4][4],
                                            OutT* __restrict__ Cblk, int ldc,
                                            int wm, int n16, int quad) {
#pragma unroll
    for (int i = 0; i < 4; i++)
#pragma unroll
        for (int j = 0; j < 4; j++)
#pragma unroll
            for (int r = 0; r < 4; r++)
                Cblk[(long)(wm + i * 16 + quad * 4 + r) * ldc + j * 16 + n16] =
                    (OutT)acc[i][j][r];
}

// Transposed epilogue for v: base = vtg + g*128*3072 + (n0&127)*3072;
// element (t = m0+wm+i*16+quad*4+r, d = j*16+n16) -> base[d*3072 + t].
__device__ __forceinline__ void gemm_epi256_vT(const f32x4 (&acc)[4][4],
                                               __bf16* __restrict__ base,
                                               int m0, int wm, int n16, int quad) {
#pragma unroll
    for (int i = 0; i < 4; i++)
#pragma unroll
        for (int j = 0; j < 4; j++) {
            bf16x4 o;
#pragma unroll
            for (int r = 0; r < 4; r++) o[r] = (__bf16)acc[i][j][r];
            *(bf16x4*)(base + (long)(j * 16 + n16) * 3072 +
                       (m0 + wm + i * 16 + quad * 4)) = o;
        }
}

__device__ __forceinline__ void gemm25664_bb_core(__bf16 (&As)[256][64],
                                                  __bf16 (&Bs)[64][64],
                                                  const __bf16* __restrict__ Ablk,
                                                  const __bf16* __restrict__ Bblk,
                                                  f32x4 (&acc)[4][4],
                                                  int K, int lda, int ldb) {
    const int tid  = threadIdx.x;
    const int lane = tid & 63;
    const int w    = tid >> 6;
    const int n16  = lane & 15;
    const int quad = lane >> 4;
    const int wm   = w * 64;

    // Linear LDS dest (gload_lds: wave-uniform base + lane*16); source col
    // pre-XORed so LDS[r][chunk c] holds global chunk c^(r&7).
    const int arow  = w * 64 + (lane >> 3);       // A rows, +8i (i=0..7)
    const int brow  = w * 16 + (lane >> 3);       // B rows, +8i (i=0..1)
    const int sxor  = (lane >> 3) & 7;            // == arow&7 == brow&7
    const int scol  = (lane & 7) * 8;
    const int sgcol = ((lane & 7) ^ sxor) * 8;
    const __bf16* Ap = Ablk + (long)arow * lda + sgcol;
    const __bf16* Bp = Bblk + (long)brow * ldb + sgcol;
    const int rx = n16 & 7;

    for (int k0 = 0; k0 < K; k0 += 64) {
#pragma unroll
        for (int i = 0; i < 8; i++)
            load_lds16(Ap + (long)i * 8 * lda + k0, &As[arow + i * 8][scol]);
#pragma unroll
        for (int i = 0; i < 2; i++)
            load_lds16(Bp + (long)i * 8 * ldb + k0, &Bs[brow + i * 8][scol]);
        __syncthreads();
        gemm_compute256(As, Bs, acc, wm, n16, quad, rx);
        __syncthreads();
    }
}

template <typename OutT>
__device__ __forceinline__ void gemm25664_fb(__bf16 (&As)[256][64], __bf16 (&Bs)[64][64],
                                             const __bf16* __restrict__ Ablk,
                                             const float* __restrict__ Bblk,
                                             OutT* __restrict__ Cblk,
                                             int K, int lda, int ldb, int ldc) {
    const int tid  = threadIdx.x;
    const int lane = tid & 63;
    const int w    = tid >> 6;
    const int n16  = lane & 15;
    const int quad = lane >> 4;
    const int wm   = w * 64;

    f32x4 acc[4][4];
    const f32x4 fzero = {0.f, 0.f, 0.f, 0.f};
#pragma unroll
    for (int i = 0; i < 4; i++)
#pragma unroll
        for (int j = 0; j < 4; j++) acc[i][j] = fzero;

    const int arow  = w * 64 + (lane >> 3);
    const int sxor  = (lane >> 3) & 7;
    const int scol  = (lane & 7) * 8;
    const int sgcol = ((lane & 7) ^ sxor) * 8;
    const __bf16* Ap = Ablk + (long)arow * lda + sgcol;

    // B: one row per thread (64 rows x 64 fp32 cols = 16 consecutive floats
    // per thread), reg-staged, cvt->bf16, swizzled ds_write (2 chunks).
    const int brr  = tid >> 2;                    // B row 0..63
    const int bc0  = (tid & 3) * 16;              // first of 16 fp32 cols
    const int bch  = (tid & 3) * 2;               // first of 2 bf16x8 chunks
    const int bxor = brr & 7;
    const float* Bptr = Bblk + (long)brr * ldb + bc0;

    const int rx = n16 & 7;
    float4 breg[4];

#define LOAD_B(kk)                                                             \
    _Pragma("unroll") for (int i = 0; i < 4; i++)                              \
        breg[i] = *(const float4*)(Bptr + (kk) + i * 4);

    LOAD_B(0);
    for (int k0 = 0; k0 < K; k0 += 64) {
#pragma unroll
        for (int i = 0; i < 8; i++)
            load_lds16(Ap + (long)i * 8 * lda + k0, &As[arow + i * 8][scol]);
        {
            bf16x8 b0, b1;
#pragma unroll
            for (int j = 0; j < 4; j++) {
                b0[j]     = (__bf16)breg[0][j]; b0[j + 4] = (__bf16)breg[1][j];
                b1[j]     = (__bf16)breg[2][j]; b1[j + 4] = (__bf16)breg[3][j];
            }
            *(bf16x8*)&Bs[brr][((bch + 0) ^ bxor) * 8] = b0;
            *(bf16x8*)&Bs[brr][((bch + 1) ^ bxor) * 8] = b1;
        }
        if (k0 + 64 < K) LOAD_B(k0 + 64);   // in flight across compute below
        __syncthreads();
        gemm_compute256(As, Bs, acc, wm, n16, quad, rx);
        __syncthreads();
    }
#undef LOAD_B
    gemm_epi256(acc, Cblk, ldc, wm, n16, quad);
}

// ---------------------------------------------------------------------------
// Fused k + v + q projections, 640 blocks (all resident at 4/CU LDS cap).
// v output written TRANSPOSED straight to vtg[g][d][t] (R17-verified).
// ---------------------------------------------------------------------------
__global__ __launch_bounds__(256, 4) void gemm_kvq(const __bf16* __restrict__ tgtb,
                                                   const __bf16* __restrict__ hidb,
                                                   const __bf16* __restrict__ wkb,
                                                   const __bf16* __restrict__ wvb,
                                                   const float* __restrict__ wq,
                                                   __bf16* __restrict__ kbf,
                                                   __bf16* __restrict__ vtg,
                                                   __bf16* __restrict__ qbf) {
    __shared__ __bf16 As[256][64];
    __shared__ __bf16 Bs[64][64];
    const int tid  = threadIdx.x;
    const int lane = tid & 63;
    const int w    = tid >> 6;
    const int n16  = lane & 15;
    const int quad = lane >> 4;
    const int wm   = w * 64;

    const int bid = blockIdx.x;
    const int b = (bid & 7) * 80 + (bid >> 3);    // bijective: 640 = 8*80
    if (b < 384) {
        const int z = b >= 192, t = b - z * 192;
        const int m0 = (t >> 4) * 256, n0 = (t & 15) * 64;
        const __bf16* Ap = (m0 < 2048) ? tgtb + (long)m0 * 2048
                                       : hidb + (long)(m0 - 2048) * 2048;
        const __bf16* Bp = (z ? wvb : wkb) + (long)n0 * 2048;
        f32x4 acc[4][4];
        const f32x4 fzero = {0.f, 0.f, 0.f, 0.f};
#pragma unroll
        for (int i = 0; i < 4; i++)
#pragma unroll
            for (int j = 0; j < 4; j++) acc[i][j] = fzero;
        gemm25664_bb_core(As, Bs, Ap, Bp, acc, 2048, 2048, 2048);
        if (z) {
            __bf16* base = vtg + (long)(n0 >> 7) * 128 * 3072 + (long)(n0 & 127) * 3072;
            gemm_epi256_vT(acc, base, m0, wm, n16, quad);
        } else {
            gemm_epi256<__bf16>(acc, kbf + (long)m0 * 1024 + n0, 1024, wm, n16, quad);
        }
    } else {
        const int t = b - 384;
        const int m0 = (t >> 6) * 256, n0 = (t & 63) * 64;
        gemm25664_fb<__bf16>(As, Bs, hidb + (long)m0 * 2048, wq + (long)n0 * 2048,
                             qbf + (long)m0 * 4096 + n0, 2048, 2048, 2048, 4096);
    }
}

// ---------------------------------------------------------------------------
// Output projection: 256x64 tiles, split-K=4, B = fp32 wo direct (fb path).
// ---------------------------------------------------------------------------
__global__ __launch_bounds__(256, 4) void gemm_wo4(const __bf16* __restrict__ A,
                                                   const float* __restrict__ wo,
                                                   float* __restrict__ out,
                                                   float* __restrict__ p1,
                                                   float* __restrict__ p2,
                                                   float* __restrict__ p3) {
    __shared__ __bf16 As[256][64];
    __shared__ __bf16 Bs[64][64];
    const int bid = blockIdx.x;
    const int b = (bid & 7) * 64 + (bid >> 3);    // bijective: 512 = 8*64
    const int z = b >> 7, t = b & 127;            // 4m x 32n per z
    const int m0 = (t >> 5) * 256, n0 = (t & 31) * 64;
    float* C;
    switch (z) {
        case 0:  C = out; break;
        case 1:  C = p1;  break;
        case 2:  C = p2;  break;
        default: C = p3;  break;
    }
    gemm25664_fb<float>(As, Bs, A + (long)m0 * 4096 + z * 1024,
                        wo + (long)n0 * 4096 + z * 1024,
                        C + (long)m0 * 2048 + n0, 1024, 4096, 4096, 2048);
}

__global__ __launch_bounds__(256) void add4_wo(float* __restrict__ out,
                                               const float* __restrict__ p1,
                                               const float* __restrict__ p2,
                                               const float* __restrict__ p3, int n4) {
    int i = blockIdx.x * 256 + threadIdx.x;
    int stride = gridDim.x * 256;
    for (; i < n4; i += stride) {
        float4 a = ((const float4*)out)[i];
        float4 b = ((const float4*)p1)[i];
        float4 c = ((const float4*)p2)[i];
        float4 d = ((const float4*)p3)[i];
        float4 o;
        o.x = (a.x + b.x) + (c.x + d.x);
        o.y = (a.y + b.y) + (c.y + d.y);
        o.z = (a.z + b.z) + (c.z + d.z);
        o.w = (a.w + b.w) + (c.w + d.w);
        ((float4*)out)[i] = o;
    }
}

// ---------------------------------------------------------------------------
// Fused RMSNorm+RoPE for q (z=0) and k (z=1), in place.
// ---------------------------------------------------------------------------
__global__ __launch_bounds__(256) void rmsnorm_rope2(__bf16* __restrict__ xq,
                                                     const float* __restrict__ wq,
                                                     __bf16* __restrict__ xk,
                                                     const float* __restrict__ wk,
                                                     const float* __restrict__ cosb,
                                                     const float* __restrict__ sinb) {
    const int z = blockIdx.y;
    __bf16*      x = z ? xk : xq;
    const float* w = z ? wk : wq;
    const int nheads     = z ? 8 : 32;
    const int row_stride = z ? 1024 : 4096;
    const int pos_offset = z ? 0 : 2048;
    const float outscale = z ? 1.0f : 0.08838834764831845f;
    const int nitems     = z ? 3072 * 8 : 1024 * 32;

    int item = blockIdx.x * 4 + (threadIdx.x >> 6);
    int lane = threadIdx.x & 63;
    if (item >= nitems) return;
    int row = item / nheads;
    int head = item - row * nheads;
    __bf16* p = x + (long)row * row_stride + head * HD;

    float x1 = (float)p[lane], x2 = (float)p[lane + 64];
    float ss = x1 * x1 + x2 * x2;
#pragma unroll
    for (int o = 32; o >= 1; o >>= 1) ss += __shfl_xor(ss, o);
    float r = rsqrtf(ss * (1.0f / 128.0f) + 1e-6f) * outscale;

    int pos = pos_offset + row;
    float c1 = cosb[pos * HD + lane], c2 = cosb[pos * HD + lane + 64];
    float s1 = sinb[pos * HD + lane], s2 = sinb[pos * HD + lane + 64];
    float y1 = x1 * r * w[lane];
    float y2 = x2 * r * w[lane + 64];
    p[lane]      = (__bf16)(y1 * c1 - y2 * s1);
    p[lane + 64] = (__bf16)(y2 * c2 + y1 * s2);
}

// ---------------------------------------------------------------------------
// Split-K flash attention. R19 = R17 structure + the R18 LDS XOR-swizzle
// ONLY (isolated; R18's failure was the wqb workspace overflow, not this).
// R17 counters: SQ_LDS_BANK_CONFLICT 5.37M ~ 11% of dispatch with pad-only
// strides; GEMM's XOR swizzle measured exactly 0. All flash staging is
// reg-staged (plain ds_write), so BOTH write and read cols take
// chunk ^= (row&7) — write stores logical chunk c at physical c^(row&7);
// every fragment-read row has row&7 == n&7 == rx (all row bases are
// multiples of 8), so reads use physical (c^rx). Natural row strides
// (128/64/64 elems); LDS 53248 -> 49152 B.
// Structure: 2-way split-K, separate Ps (2 barriers/step), inline K/V
// staging (120 VGPR, under the 128 cliff).
// ---------------------------------------------------------------------------
__global__ __launch_bounds__(256) void flash_attn_splitk(const __bf16* __restrict__ qb,
                                                         const __bf16* __restrict__ kb,
                                                         const __bf16* __restrict__ vtg,
                                                         __bf16* __restrict__ Opart0,
                                                         __bf16* __restrict__ Opart1,
                                                         float* __restrict__ lsum) {
    __shared__ __bf16 Ks[64][128];     // 16 KB, chunk-XOR swizzled
    __shared__ __bf16 Vs[128][64];     // 16 KB, chunk-XOR swizzled
    __shared__ __bf16 Ps[4][32][64];   // 16 KB, chunk-XOR swizzled (per-wave)

    const int tid  = threadIdx.x;
    const int lane = tid & 63;
    const int w    = tid >> 6;
    const int n    = lane & 15;
    const int quad = lane >> 4;
    const int rx   = n & 7;            // read-side row XOR (lane-const)

    const int bid = blockIdx.x;        // 0..255
    const int s   = blockIdx.y;        // 0..1
    const int g  = bid & 7;
    const int jj = bid >> 3;           // 0..31
    const int h  = g * 4 + (jj & 3);
    const int qt = jj >> 2;            // 0..7, 128-row q tiles

    const int qr0 = qt * 128 + w * 16; // m-tile 0 base; m-tile 1 = +64

    bf16x8 qf[2][4];
#pragma unroll
    for (int mt = 0; mt < 2; mt++) {
        const __bf16* qp = qb + (long)(qr0 + mt * 64 + n) * 4096 + h * 128 + quad * 8;
        qf[mt][0] = *(const bf16x8*)(qp);
        qf[mt][1] = *(const bf16x8*)(qp + 32);
        qf[mt][2] = *(const bf16x8*)(qp + 64);
        qf[mt][3] = *(const bf16x8*)(qp + 96);
    }

    f32x4 O[2][8];
    const f32x4 fzero = {0.f, 0.f, 0.f, 0.f};
#pragma unroll
    for (int mt = 0; mt < 2; mt++)
#pragma unroll
        for (int dt = 0; dt < 8; dt++) O[mt][dt] = fzero;
    float l_loc[2] = {0.f, 0.f};       // lane-local: lane n16 owns q-row qr0+mt*64+n

    const int ntot = 34 + 2 * qt;      // even
    const int half = ntot >> 1;
    const int tbeg = s ? half : 0;
    const int tend = s ? ntot : half;

    // staging indices: global source LINEAR; LDS write col chunk-XOR swizzled
    const int krr = tid >> 4;                      // K rows krr+16i, i=0..3
    const int kcg = (tid & 15) * 8;                // global col (elems)
    const int kcw = ((tid & 15) ^ (krr & 7)) * 8;  // swizzled LDS col
    const int vrr = tid >> 3;                      // V rows vrr+32i, i=0..3
    const int vcg = (tid & 7) * 8;
    const int vcw = ((tid & 7) ^ (vrr & 7)) * 8;
    const __bf16* kp = kb + g * 128 + (long)(tbeg * 64 + krr) * 1024 + kcg;
    const __bf16* vp = vtg + (long)g * 128 * 3072 + (long)vrr * 3072 + tbeg * 64 + vcg;

    for (int tt = tbeg; tt < tend; tt++) {
        // inline K/V staging (global -> reg -> LDS, compiler-scheduled)
#pragma unroll
        for (int i = 0; i < 4; i++)
            *(bf16x8*)&Ks[krr + i * 16][kcw] = *(const bf16x8*)(kp + (long)i * 16 * 1024);
#pragma unroll
        for (int i = 0; i < 4; i++)
            *(bf16x8*)&Vs[vrr + i * 32][vcw] = *(const bf16x8*)(vp + (long)i * 32 * 3072);
        kp += 64 * 1024;
        vp += 64;
        __syncthreads();   // staged K/V tile visible to all waves

        // S^T = K Q^T: A = K-frag, B = Q-frag (identical lane layouts).
        // Result: col(lane&15) = q-row, row(quad*4+r) = key t.
        f32x4 S[2][4];
#pragma unroll
        for (int nt = 0; nt < 4; nt++) {
            f32x4 a0 = fzero, a1 = fzero;
#pragma unroll
            for (int ks = 0; ks < 4; ks++) {
                bf16x8 kf = *(const bf16x8*)&Ks[nt * 16 + n][((ks * 4 + quad) ^ rx) * 8];
                a0 = MFMA16(kf, qf[0][ks], a0);
                a1 = MFMA16(kf, qf[1][ks], a1);
            }
            S[0][nt] = a0;
            S[1][nt] = a1;
        }

        if (tt >= ntot - 2) {   // diagonal band spans the last two tiles
            const int t0 = tt * 64;
#pragma unroll
            for (int mt = 0; mt < 2; mt++) {
                const int lim = 2048 + qr0 + mt * 64 + n;   // q-row = lane index
#pragma unroll
                for (int nt = 0; nt < 4; nt++)
#pragma unroll
                    for (int r = 0; r < 4; r++) {
                        int t = t0 + nt * 16 + quad * 4 + r;
                        if (t > lim) S[mt][nt][r] = -1e30f;
                    }
            }
        }

        // fixed-shift softmax; row-sum is lane-local (lane owns its q-row)
#pragma unroll
        for (int mt = 0; mt < 2; mt++)
#pragma unroll
            for (int nt = 0; nt < 4; nt++)
#pragma unroll
                for (int r = 0; r < 4; r++) {
                    float p = __expf(S[mt][nt][r] - MSTATIC);
                    S[mt][nt][r] = p;
                    l_loc[mt] += p;
                }

        // P -> LDS (per-wave private region; same-wave DS ordering suffices).
        // elem col t = nt*16+quad*4: 16B-chunk = nt*2+(quad>>1) -> XOR rx;
        // 8B-half offset = (quad&1)*4 elems.
#pragma unroll
        for (int mt = 0; mt < 2; mt++)
#pragma unroll
            for (int nt = 0; nt < 4; nt++) {
                bf16x4 pk;
#pragma unroll
                for (int r = 0; r < 4; r++) pk[r] = (__bf16)S[mt][nt][r];
                *(bf16x4*)&Ps[w][mt * 16 + n]
                    [(((nt * 2 + (quad >> 1)) ^ rx) * 8) + (quad & 1) * 4] = pk;
            }

        bf16x8 pa[2][2];
#pragma unroll
        for (int mt = 0; mt < 2; mt++)
#pragma unroll
            for (int kg = 0; kg < 2; kg++)
                pa[mt][kg] = *(const bf16x8*)&Ps[w][mt * 16 + n]
                                 [((kg * 4 + quad) ^ rx) * 8];

#pragma unroll
        for (int dt = 0; dt < 8; dt++) {
            bf16x8 vf0 = *(const bf16x8*)&Vs[dt * 16 + n][(quad ^ rx) * 8];
            bf16x8 vf1 = *(const bf16x8*)&Vs[dt * 16 + n][((4 + quad) ^ rx) * 8];
#pragma unroll
            for (int mt = 0; mt < 2; mt++) {
                f32x4 acc = O[mt][dt];
                acc = MFMA16(pa[mt][0], vf0, acc);
                acc = MFMA16(pa[mt][1], vf1, acc);
                O[mt][dt] = acc;
            }
        }

        __syncthreads();   // all Ks/Vs reads done; next tile may be written
    }

    // row-sum: reduce across the 4 quads (lane already holds its row's partial)
#pragma unroll
    for (int mt = 0; mt < 2; mt++) {
        float sm = l_loc[mt];
        sm += __shfl_xor(sm, 16);
        sm += __shfl_xor(sm, 32);
        l_loc[mt] = sm;
    }

    __bf16* Op = s ? Opart1 : Opart0;
    const long tb = (long)(h * 8 + qt) * 128 * 128;
#pragma unroll
    for (int mt = 0; mt < 2; mt++)
#pragma unroll
        for (int dt = 0; dt < 8; dt++)
#pragma unroll
            for (int r = 0; r < 4; r++)
                Op[tb + (long)(mt * 64 + w * 16 + quad * 4 + r) * 128 + dt * 16 + n] =
                    (__bf16)O[mt][dt][r];
    if (quad == 0) {
        const int lb = (s * 256 + h * 8 + qt) * 128 + w * 16;
#pragma unroll
        for (int mt = 0; mt < 2; mt++)
            lsum[lb + mt * 64 + n] = l_loc[mt];
    }
}

// ---------------------------------------------------------------------------
// Additive merge of 2 split-K partials -> normalized bf16 attn-out.
// ---------------------------------------------------------------------------
__global__ __launch_bounds__(256) void flash_merge(const __bf16* __restrict__ O0,
                                                   const __bf16* __restrict__ O1,
                                                   const float* __restrict__ lsum,
                                                   __bf16* __restrict__ ob) {
    const int bx = blockIdx.x;         // 512: (h, qt, half64)
    const int h   = bx >> 4;
    const int r6  = bx & 15;
    const int qt  = r6 >> 1;
    const int sub = r6 & 1;
    const int row  = threadIdx.x >> 2;
    const int cseg = (threadIdx.x & 3) * 32;
    const int mrow = sub * 64 + row;

    const int tilei = h * 8 + qt;
    float inv = 1.0f / (lsum[tilei * 128 + mrow] + lsum[(256 + tilei) * 128 + mrow]);

    const long src = (long)tilei * 128 * 128 + (long)mrow * 128 + cseg;
    __bf16* dst = ob + (long)(qt * 128 + mrow) * 4096 + h * 128 + cseg;
#pragma unroll
    for (int j = 0; j < 4; j++) {
        bf16x8 x0 = *(const bf16x8*)(O0 + src + j * 8);
        bf16x8 x1 = *(const bf16x8*)(O1 + src + j * 8);
        bf16x8 o;
#pragma unroll
        for (int k = 0; k < 8; k++)
            o[k] = (__bf16)(((float)x0[k] + (float)x1[k]) * inv);
        *(bf16x8*)(dst + j * 8) = o;
    }
}

// ---------------------------------------------------------------------------
extern "C" void kernel_launch(void* const* d_in, const int* in_sizes, int n_in,
                              void* d_out, int out_size, void* d_ws, size_t ws_size,
                              hipStream_t stream) {
    const float* hidden = (const float*)d_in[0];
    const float* target = (const float*)d_in[1];
    const float* cosb   = (const float*)d_in[2];
    const float* sinb   = (const float*)d_in[3];
    const float* wq = (const float*)d_in[5];
    const float* wk = (const float*)d_in[6];
    const float* wv = (const float*)d_in[7];
    const float* wo = (const float*)d_in[8];
    const float* qw = (const float*)d_in[9];
    const float* kw = (const float*)d_in[10];
    float* out = (float*)d_out;

    // 40 MB workspace overlays (launch order guarantees safety), R17 layout:
    //   phase A (conv/kvq):   kbf@0-6, vtg@6-12 (v written transposed by kvq)
    //                         hidb@20-24 tgtb@24-32 wkb@32-36 wvb@36-40
    //   phase B (flash):      reads kbf@0-6, vtg@6-12, qbf(d_out)
    //                         writes Op0@12-20 Op1@20-28 lbuf@36-36.3
    //   phase C (merge):      writes attnb@0-8
    //   phase D (wo4/add4):   po1@8-16 po2@16-24 po3@28-36, out=d_out
    char* ws = (char*)d_ws;
    const long MB = 1 << 20;
    __bf16* kbf  = (__bf16*)(ws);             // @0..6
    __bf16* vtg  = (__bf16*)(ws + 6 * MB);    // @6..12  (written by kvq)
    __bf16* hidb = (__bf16*)(ws + 20 * MB);   // @20..24
    __bf16* tgtb = (__bf16*)(ws + 24 * MB);   // @24..32
    __bf16* wkb  = (__bf16*)(ws + 32 * MB);   // @32..36
    __bf16* wvb  = (__bf16*)(ws + 36 * MB);   // @36..40
    __bf16* Op0  = (__bf16*)(ws + 12 * MB);   // @12..20 (post-kvq)
    __bf16* Op1  = (__bf16*)(ws + 20 * MB);   // @20..28 (post-kvq)
    float*  lbuf = (float*)(ws + 36 * MB);    // @36..36.3 (post-kvq)
    __bf16* attnb= (__bf16*)(ws);             // @0..8   (post-flash)
    float*  po1  = (float*)(ws + 8 * MB);     // @8..16  (post-merge)
    float*  po2  = (float*)(ws + 16 * MB);    // @16..24 (post-merge)
    float*  po3  = (float*)(ws + 28 * MB);    // @28..36 (post-merge)
    __bf16* qbf  = (__bf16*)d_out;            // 8MB: q / dead after flash

    dim3 blk(256);

    // activations + k/v weights -> bf16
    conv4_f32_bf16<<<dim3(1024, 4), blk, 0, stream>>>(
        hidden, hidb, (1024 * 2048) / 4, target, tgtb, (2048 * 2048) / 4,
        wk, wkb, (1024 * 2048) / 4, wv, wvb, (1024 * 2048) / 4);

    // all three projections, one launch; v stored transposed (no transpose_v)
    gemm_kvq<<<640, blk, 0, stream>>>(tgtb, hidb, wkb, wvb, wq, kbf, vtg, qbf);

    // fused RMSNorm + RoPE (q and k)
    rmsnorm_rope2<<<dim3(8192, 2), blk, 0, stream>>>(qbf, qw, kbf, kw, cosb, sinb);

    // 2-way split-K flash attention (512 blocks) + additive merge
    flash_attn_splitk<<<dim3(256, 2), blk, 0, stream>>>(qbf, kbf, vtg,
                                                        Op0, Op1, lbuf);
    flash_merge<<<512, blk, 0, stream>>>(Op0, Op1, lbuf, attnb);

    // output projection: 256x64 fb tiles, split-K=4 (512 blocks) + reduce
    gemm_wo4<<<512, blk, 0, stream>>>(attnb, wo, out, po1, po2, po3);
    add4_wo<<<1024, blk, 0, stream>>>(out, po1, po2, po3, (1024 * 2048) / 4);
}